// Round 7
// baseline (340.465 us; speedup 1.0000x reference)
//
#include <hip/hip_runtime.h>
#include <math.h>

// ---- problem dims ----
constexpr int cB = 8, cN = 2048, cI = 64, cH = 128, cO = 8, cK = 24;
constexpr int ROWS = cB * cN; // 16384

// ---- ws layout (floats) ----
constexpr size_t WS_SPATIAL = 0;                                  // 16384*128
constexpr size_t WS_SQ      = WS_SPATIAL + (size_t)ROWS * cH;     // 16384
constexpr size_t WS_GHS     = WS_SQ + ROWS;                       // 8*384
constexpr size_t WS_NSQ0    = WS_GHS + (size_t)cO * 3 * cH;       // 8
constexpr size_t WS_NEWOBJ  = WS_NSQ0 + cO;                       // 8*8*128
constexpr size_t WS_NSQ     = WS_NEWOBJ + (size_t)cB * cO * cH;   // 64
constexpr size_t WS_W1T     = WS_NSQ + (size_t)cB * cO;           // 16*128*4  = 8192
constexpr size_t WS_W2T     = WS_W1T + 8192;                      // 32*128*4  = 16384
constexpr size_t WS_HW1T    = WS_W2T + 16384;                     // 33*128*4  = 16896
constexpr size_t WS_UPD3    = WS_HW1T + 16896;                    // 3*8*24*128
constexpr size_t WS_S3      = WS_UPD3 + (size_t)3 * cB * cK * cH; // 3*8*24
constexpr size_t WS_XBF     = WS_S3 + (size_t)3 * cB * cK;        // 16384*64 bf16 = 524288 floats

// ---- d_out layout (floats), return order: slots, attn, pred_time, density ----
constexpr size_t OUT_SLOTS = 0;                                   // 8*24*129
constexpr size_t OUT_ATTN  = (size_t)cB * cK * 129;
constexpr size_t OUT_PT    = OUT_ATTN + (size_t)cB * cK * cN;
constexpr size_t OUT_DEN   = OUT_PT + (size_t)cB * cN;

typedef __attribute__((ext_vector_type(8))) short bf16x8;
typedef __attribute__((ext_vector_type(4))) float f32x4;

__device__ __forceinline__ float gelu_f(float v){
  return 0.5f * v * (1.f + erff(v * 0.70710678118654752440f));
}
__device__ __forceinline__ short f2bf(float f){
  unsigned u = __float_as_uint(f);
  u += 0x7fffu + ((u >> 16) & 1u);   // RNE
  return (short)(u >> 16);
}
__device__ __forceinline__ bf16x8 pack8(float4 a, float4 b){
  bf16x8 r;
  r[0]=f2bf(a.x); r[1]=f2bf(a.y); r[2]=f2bf(a.z); r[3]=f2bf(a.w);
  r[4]=f2bf(b.x); r[5]=f2bf(b.y); r[6]=f2bf(b.z); r[7]=f2bf(b.w);
  return r;
}
__device__ __forceinline__ float wred(float a){   // full-wave (64) butterfly sum
  a += __shfl_xor(a, 1); a += __shfl_xor(a, 2); a += __shfl_xor(a, 4);
  a += __shfl_xor(a, 8); a += __shfl_xor(a, 16); a += __shfl_xor(a, 32);
  return a;
}

// ---------------- x -> bf16 copy (RNE) + sq[b,n] = ||x||^2, fused & coalesced ----------------
__global__ __launch_bounds__(256) void k_cvt_sq(const float* __restrict__ x, short* __restrict__ xbf,
                                                float* __restrict__ sq){
  int t = threadIdx.x;
  size_t base = (size_t)blockIdx.x * 2048;   // floats
  int r = t >> 3, e0 = (t & 7) * 8;
  const float4* xp = (const float4*)(x + base + (size_t)r * cI + e0);
  float4 v0 = xp[0], v1 = xp[1];
  *(bf16x8*)(xbf + base + (size_t)r * cI + e0) = pack8(v0, v1);
  float s = v0.x*v0.x + v0.y*v0.y + v0.z*v0.z + v0.w*v0.w
          + v1.x*v1.x + v1.y*v1.y + v1.z*v1.z + v1.w*v1.w;
  s += __shfl_xor(s, 1); s += __shfl_xor(s, 2); s += __shfl_xor(s, 4);
  if ((t & 7) == 0) sq[blockIdx.x * 32 + r] = s;
}

// ---------------- prep: ghs, ||obj||^2, transposed d-chunked weight copies ----------------
__global__ __launch_bounds__(256) void k_prep(const float* __restrict__ objsp, const float* __restrict__ w_hh,
                                              const float* __restrict__ b_hh,
                                              const float* __restrict__ ew1, const float* __restrict__ ew2,
                                              const float* __restrict__ spw1,
                                              float* __restrict__ ghs, float* __restrict__ nsq0,
                                              float* __restrict__ w1t, float* __restrict__ w2t,
                                              float* __restrict__ hw1t){
  int id = blockIdx.x * 256 + threadIdx.x;
  if (id < cO * 3 * cH){
    int o = id / (3 * cH), j = id % (3 * cH);
    const float* wr = w_hh + (size_t)j * cH;
    const float* ob = objsp + (size_t)o * cH;
    float a0=0,a1=0,a2=0,a3=0;
    #pragma unroll
    for (int h = 0; h < cH; h += 4){
      a0 += wr[h]*ob[h]; a1 += wr[h+1]*ob[h+1]; a2 += wr[h+2]*ob[h+2]; a3 += wr[h+3]*ob[h+3];
    }
    ghs[id] = (a0+a1)+(a2+a3) + b_hh[j];
  } else if (id < cO * 3 * cH + cO){
    int o = id - cO * 3 * cH;
    const float* ob = objsp + (size_t)o * cH;
    float s = 0.f;
    for (int h = 0; h < cH; ++h) s += ob[h]*ob[h];
    nsq0[o] = s;
  } else {
    int idx = id - (cO * 3 * cH + cO);
    if (idx < 8192){                       // w1t: 16 dc
      int dc = idx >> 9, rem = idx & 511, f = rem >> 2, j = rem & 3;
      w1t[idx] = ew1[f * cI + dc * 4 + j];
    } else if (idx < 24576){               // w2t: 32 dc
      int k2 = idx - 8192;
      int dc = k2 >> 9, rem = k2 & 511, f = rem >> 2, j = rem & 3;
      w2t[k2] = ew2[f * cH + dc * 4 + j];
    } else if (idx < 41472){               // hw1t: 33 dc (d=128 -> den weight; 129..131 zero)
      int k3 = idx - 24576;
      int dc = k3 >> 9, rem = k3 & 511, f = rem >> 2, j = rem & 3;
      int d = dc * 4 + j;
      hw1t[k3] = (d < 129) ? spw1[f * 129 + d] : 0.f;
    }
  }
}

// ---------------- pairwise distances (pre-converted bf16) + fused per-row top-6 -> density ----------------
__global__ __launch_bounds__(256) void k_pairwise(const short* __restrict__ xbf, const float* __restrict__ sq,
                                                  float* __restrict__ den_out){
  __shared__ float cand[4][16][101];
  int b  = blockIdx.x >> 7;
  int rt = blockIdx.x & 127;
  int r0 = rt * 16;
  int lane = threadIdx.x & 63, w = threadIdx.x >> 6;
  const short* xb = xbf + (size_t)b * cN * cI;

  int arow = r0 + (lane & 15);
  int koff = (lane >> 4) * 8;
  const bf16x8* ap = (const bf16x8*)(xb + (size_t)arow * cI + koff);
  bf16x8 a0 = ap[0];
  bf16x8 a1 = ap[4];

  float sqr[4];
  int rg0 = r0 + ((lane >> 4) << 2);
  #pragma unroll
  for (int j = 0; j < 4; ++j) sqr[j] = sq[b * cN + rg0 + j];

  float t6[4][6];
  #pragma unroll
  for (int j = 0; j < 4; ++j){
    #pragma unroll
    for (int q = 0; q < 6; ++q) t6[j][q] = 3e38f;
  }

  int cbase = w * 512;
  #pragma unroll 2
  for (int ct = 0; ct < 32; ++ct){
    int col0 = cbase + ct * 16;
    int brow = col0 + (lane & 15);
    const bf16x8* bp = (const bf16x8*)(xb + (size_t)brow * cI + koff);
    bf16x8 b0 = bp[0];
    bf16x8 b1 = bp[4];
    f32x4 acc = {0.f, 0.f, 0.f, 0.f};
    acc = __builtin_amdgcn_mfma_f32_16x16x32_bf16(a0, b0, acc, 0, 0, 0);
    acc = __builtin_amdgcn_mfma_f32_16x16x32_bf16(a1, b1, acc, 0, 0, 0);
    float sqc = sq[b * cN + col0 + (lane & 15)];
    #pragma unroll
    for (int j = 0; j < 4; ++j){
      float d2 = sqr[j] + sqc - 2.f * acc[j];
      d2 = fmaxf(d2, 0.f);
      if (d2 < t6[j][5]){
        if (d2 < t6[j][4]){ t6[j][5]=t6[j][4];
          if (d2 < t6[j][3]){ t6[j][4]=t6[j][3];
            if (d2 < t6[j][2]){ t6[j][3]=t6[j][2];
              if (d2 < t6[j][1]){ t6[j][2]=t6[j][1];
                if (d2 < t6[j][0]){ t6[j][1]=t6[j][0]; t6[j][0]=d2; } else t6[j][1]=d2;
              } else t6[j][2]=d2;
            } else t6[j][3]=d2;
          } else t6[j][4]=d2;
        } else t6[j][5]=d2;
      }
    }
  }
  int rloc = (lane >> 4) << 2;
  #pragma unroll
  for (int j = 0; j < 4; ++j){
    #pragma unroll
    for (int q = 0; q < 6; ++q) cand[w][rloc + j][(lane & 15) * 6 + q] = t6[j][q];
  }
  __syncthreads();
  int tt = threadIdx.x;
  if (tt < 64){
    int ww = tt >> 4, rr = tt & 15;
    const float* c = cand[ww][rr];
    float m0=3e38f,m1=3e38f,m2=3e38f,m3=3e38f,m4=3e38f,m5=3e38f;
    #pragma unroll
    for (int q = 0; q < 96; ++q){
      float v = c[q];
      if (v < m5){
        if (v<m4){ m5=m4; if (v<m3){ m4=m3; if (v<m2){ m3=m2; if (v<m1){ m2=m1; if (v<m0){ m1=m0; m0=v; } else m1=v; } else m2=v; } else m3=v; } else m4=v; } else m5=v;
      }
    }
    float* cw = cand[ww][rr];
    cw[0]=m0; cw[1]=m1; cw[2]=m2; cw[3]=m3; cw[4]=m4; cw[5]=m5;
  }
  __syncthreads();
  if (tt < 16){
    float m0=3e38f,m1=3e38f,m2=3e38f,m3=3e38f,m4=3e38f,m5=3e38f;
    #pragma unroll
    for (int ww = 0; ww < 4; ++ww){
      const float* c = cand[ww][tt];
      #pragma unroll
      for (int q = 0; q < 6; ++q){
        float v = c[q];
        if (v < m5){
          if (v<m4){ m5=m4; if (v<m3){ m4=m3; if (v<m2){ m3=m2; if (v<m1){ m2=m1; if (v<m0){ m1=m0; m0=v; } else m1=v; } else m2=v; } else m3=v; } else m4=v; } else m5=v;
        }
      }
    }
    float md = (sqrtf(m1)+sqrtf(m2)+sqrtf(m3)+sqrtf(m4)+sqrtf(m5)) * 0.2f;
    den_out[b * cN + r0 + tt] = tanhf(md);
  }
}

// ---------------- fused encoder + spatial head: 4 rows/wave, 16 rows/block ----------------
__global__ __launch_bounds__(256) void k_enc_head(const float* __restrict__ x, const float* __restrict__ den_in,
    const float* __restrict__ w1t, const float* __restrict__ b1v, const float* __restrict__ g1, const float* __restrict__ bb1,
    const float* __restrict__ w2t, const float* __restrict__ b2v, const float* __restrict__ g2, const float* __restrict__ bb2,
    const float* __restrict__ hw1t, const float* __restrict__ hb1, const float* __restrict__ hg, const float* __restrict__ hbb,
    const float* __restrict__ hw2, const float* __restrict__ hb2,
    float* __restrict__ spatial, float* __restrict__ pt_out){
  __shared__ __align__(16) float xbuf[16][68];
  __shared__ __align__(16) float hbuf[16][132];
  const int t = threadIdx.x, lane = t & 63, wid = t >> 6;
  const int row0 = blockIdx.x * 16;
  const int rbase = wid * 4;
  const int f0 = lane * 2;

  {  // stage 16 x-rows (1024 floats = 256 float4)
    const float4* xs = (const float4*)(x + (size_t)row0 * cI);
    float4 v = xs[t];
    *(float4*)&xbuf[t >> 4][(t & 15) * 4] = v;
  }
  if (t < 16){
    float dn = den_in[row0 + t];
    float* hd = &hbuf[t][128];
    hd[0] = dn; hd[1] = 0.f; hd[2] = 0.f; hd[3] = 0.f;
  }
  __syncthreads();

  float2 b1p  = *(const float2*)(b1v + f0);
  float2 g1p  = *(const float2*)(g1  + f0);
  float2 bb1p = *(const float2*)(bb1 + f0);
  float2 b2p  = *(const float2*)(b2v + f0);
  float2 g2p  = *(const float2*)(g2  + f0);
  float2 bb2p = *(const float2*)(bb2 + f0);
  float2 hb1p = *(const float2*)(hb1 + f0);
  float2 hgp  = *(const float2*)(hg  + f0);
  float2 hbbp = *(const float2*)(hbb + f0);
  float2 hw2p = *(const float2*)(hw2 + f0);

  float accA[4], accB[4];

  // ---- layer 1: x(64) ----
  #pragma unroll
  for (int r = 0; r < 4; ++r){ accA[r] = b1p.x; accB[r] = b1p.y; }
  #pragma unroll 4
  for (int dc = 0; dc < 16; ++dc){
    float4 wA = *(const float4*)(w1t + ((size_t)dc * cH + f0) * 4);
    float4 wB = *(const float4*)(w1t + ((size_t)dc * cH + f0 + 1) * 4);
    #pragma unroll
    for (int r = 0; r < 4; ++r){
      float4 xv = *(const float4*)&xbuf[rbase + r][dc * 4];
      accA[r] += wA.x*xv.x + wA.y*xv.y + wA.z*xv.z + wA.w*xv.w;
      accB[r] += wB.x*xv.x + wB.y*xv.y + wB.z*xv.z + wB.w*xv.w;
    }
  }
  #pragma unroll
  for (int r = 0; r < 4; ++r){
    float sm = wred(accA[r] + accB[r]);
    float s2 = wred(accA[r]*accA[r] + accB[r]*accB[r]);
    float mean = sm * (1.f/128.f);
    float rstd = rsqrtf(s2 * (1.f/128.f) - mean*mean + 1e-5f);
    float hA = gelu_f((accA[r]-mean)*rstd*g1p.x + bb1p.x);
    float hB = gelu_f((accB[r]-mean)*rstd*g1p.y + bb1p.y);
    float2 hv = { hA, hB };
    *(float2*)&hbuf[rbase + r][f0] = hv;
  }
  __syncthreads();

  // ---- layer 2: h(128) ----
  #pragma unroll
  for (int r = 0; r < 4; ++r){ accA[r] = b2p.x; accB[r] = b2p.y; }
  #pragma unroll 4
  for (int dc = 0; dc < 32; ++dc){
    float4 wA = *(const float4*)(w2t + ((size_t)dc * cH + f0) * 4);
    float4 wB = *(const float4*)(w2t + ((size_t)dc * cH + f0 + 1) * 4);
    #pragma unroll
    for (int r = 0; r < 4; ++r){
      float4 hv = *(const float4*)&hbuf[rbase + r][dc * 4];
      accA[r] += wA.x*hv.x + wA.y*hv.y + wA.z*hv.z + wA.w*hv.w;
      accB[r] += wB.x*hv.x + wB.y*hv.y + wB.z*hv.z + wB.w*hv.w;
    }
  }
  #pragma unroll
  for (int r = 0; r < 4; ++r){
    float sm = wred(accA[r] + accB[r]);
    float s2 = wred(accA[r]*accA[r] + accB[r]*accB[r]);
    float mean = sm * (1.f/128.f);
    float rstd = rsqrtf(s2 * (1.f/128.f) - mean*mean + 1e-5f);
    float sA = (accA[r]-mean)*rstd*g2p.x + bb2p.x;
    float sB = (accB[r]-mean)*rstd*g2p.y + bb2p.y;
    float2 sv = { sA, sB };
    *(float2*)(spatial + (size_t)(row0 + rbase + r) * cH + f0) = sv;
    *(float2*)&hbuf[rbase + r][f0] = sv;
  }
  __syncthreads();

  // ---- head layer 1: [spatial(128), den, 0,0,0] via 132-dim padded input ----
  #pragma unroll
  for (int r = 0; r < 4; ++r){ accA[r] = hb1p.x; accB[r] = hb1p.y; }
  #pragma unroll 4
  for (int dc = 0; dc < 33; ++dc){
    float4 wA = *(const float4*)(hw1t + ((size_t)dc * cH + f0) * 4);
    float4 wB = *(const float4*)(hw1t + ((size_t)dc * cH + f0 + 1) * 4);
    #pragma unroll
    for (int r = 0; r < 4; ++r){
      float4 hv = *(const float4*)&hbuf[rbase + r][dc * 4];
      accA[r] += wA.x*hv.x + wA.y*hv.y + wA.z*hv.z + wA.w*hv.w;
      accB[r] += wB.x*hv.x + wB.y*hv.y + wB.z*hv.z + wB.w*hv.w;
    }
  }
  #pragma unroll
  for (int r = 0; r < 4; ++r){
    float sm = wred(accA[r] + accB[r]);
    float s2 = wred(accA[r]*accA[r] + accB[r]*accB[r]);
    float mean = sm * (1.f/128.f);
    float rstd = rsqrtf(s2 * (1.f/128.f) - mean*mean + 1e-5f);
    float e0 = gelu_f((accA[r]-mean)*rstd*hgp.x + hbbp.x);
    float e1 = gelu_f((accB[r]-mean)*rstd*hgp.y + hbbp.y);
    float part = wred(e0*hw2p.x + e1*hw2p.y);
    if (lane == r){
      float ps = part + hb2[0];
      float spl = fmaxf(ps, 0.f) + log1pf(expf(-fabsf(ps)));
      float dn = hbuf[rbase + r][128];
      pt_out[row0 + rbase + r] = 5.f - 1.5f*dn + 0.5f*spl;
    }
  }
}

// ---------------- fused attention + upd: per block = (b, 64 n's) ----------------
// phase 1: logits+softmax -> abuf LDS (write attn to global only on last iter)
// phase 2: upd[b,k,h] partial accumulate + Ssum, atomics
__global__ __launch_bounds__(256) void k_attn_upd(const float* __restrict__ spatial, const float* __restrict__ pt_in,
    const float* __restrict__ den_in, const float* __restrict__ objp, int ob_stride,
    const float* __restrict__ nsqp, int nq_stride,
    const float* __restrict__ lt, const float* __restrict__ bh, const float* __restrict__ hs,
    float* __restrict__ attn_out, int writeAttn,
    float* __restrict__ upd_raw, float* __restrict__ Ssum){
  __shared__ float abuf[24][65];
  int blk = blockIdx.x;
  int b = blk >> 5, chunk = blk & 31;
  int n0 = chunk * 64;
  int t = threadIdx.x;
  int sub = t & 3, rl = t >> 2;      // rl in [0,64)
  int id = b * cN + n0 + rl;

  { // ---- phase 1: attention ----
    float4 sv[8];
    const float4* sp4 = (const float4*)(spatial + (size_t)id * cH + sub * 32);
    #pragma unroll
    for (int i = 0; i < 8; ++i) sv[i] = sp4[i];
    float spn2 = 0.f;
    #pragma unroll
    for (int i = 0; i < 8; ++i) spn2 += sv[i].x*sv[i].x + sv[i].y*sv[i].y + sv[i].z*sv[i].z + sv[i].w*sv[i].w;

    const float* ob = objp + (size_t)b * ob_stride;
    float acc[8];
    #pragma unroll
    for (int o = 0; o < 8; ++o){
      const float4* orow = (const float4*)(ob + (size_t)o * cH + sub * 32);
      float a0=0,a1=0,a2=0,a3=0;
      #pragma unroll
      for (int i = 0; i < 8; ++i){ float4 w4 = orow[i];
        a0 += w4.x*sv[i].x; a1 += w4.y*sv[i].y; a2 += w4.z*sv[i].z; a3 += w4.w*sv[i].w; }
      acc[o] = (a0+a1)+(a2+a3);
    }
    spn2 += __shfl_xor(spn2, 1); spn2 += __shfl_xor(spn2, 2);
    #pragma unroll
    for (int o = 0; o < 8; ++o){ acc[o] += __shfl_xor(acc[o], 1); acc[o] += __shfl_xor(acc[o], 2); }

    if (sub == 0){
      const float* nq = nsqp + (size_t)b * nq_stride;
      float nsqv_[8];
      #pragma unroll
      for (int o = 0; o < 8; ++o) nsqv_[o] = nq[o];
      float pt = pt_in[id], den = den_in[id];
      float hsv = hs[0];
      float lts[3] = { lt[0], lt[1], lt[2] };
      float bhs[3] = { bh[0], bh[1], bh[2] };

      float logits[24];
      #pragma unroll
      for (int k = 0; k < 24; ++k){
        const int o = k / 3, l = k % 3;
        float dtv = pt - lts[l];
        float dr2 = fmaxf(spn2 + nsqv_[o] - 2.f * acc[o], 0.f);
        float ls  = dtv*dtv - dr2;
        float adL = sqrtf(fabsf(ls) + 1e-6f);
        float r   = sqrtf(dr2);
        float adt = fabsf(dtv);
        float hz  = fminf(fmaxf(bhs[l] + hsv * (den - 0.5f), 0.1f), 1.0f);
        float cone = hz - r / (adt + 1e-6f) - 10.f * fmaxf(-dtv, 0.f) - 5.f * fmaxf(r - adt, 0.f);
        logits[k] = (-adL + 0.5f * tanhf(cone)) * 10.f;
      }
      float mx = -3e38f;
      #pragma unroll
      for (int k = 0; k < 24; ++k) mx = fmaxf(mx, logits[k]);
      float es[24]; float ssum = 0.f;
      #pragma unroll
      for (int k = 0; k < 24; ++k){ es[k] = expf(logits[k] - mx); ssum += es[k]; }
      float inv = 1.f / ssum;
      #pragma unroll
      for (int k = 0; k < 24; ++k) abuf[k][rl] = es[k] * inv;
    }
  }
  __syncthreads();

  if (writeAttn){  // coalesced copy LDS -> global (last iteration only)
    float* ao = attn_out + (size_t)b * cK * cN + n0;
    #pragma unroll
    for (int i = 0; i < 6; ++i){
      int idx = t + i * 256;
      ao[(size_t)(idx >> 6) * cN + (idx & 63)] = abuf[idx >> 6][idx & 63];
    }
  }

  // ---- phase 2: upd accumulate ----
  int h = t & 127, g = t >> 7;
  float acc2[12];
  #pragma unroll
  for (int kk = 0; kk < 12; ++kk) acc2[kk] = 0.f;
  const float* sp = spatial + ((size_t)b * cN + n0) * cH + h;
  for (int ni = 0; ni < 64; ++ni){
    float spv = sp[(size_t)ni * cH];
    #pragma unroll
    for (int kk = 0; kk < 12; ++kk) acc2[kk] += abuf[g*12+kk][ni] * spv;
  }
  #pragma unroll
  for (int kk = 0; kk < 12; ++kk)
    atomicAdd(&upd_raw[((size_t)b * cK + g*12+kk) * cH + h], acc2[kk]);
  if (t < 24){
    float s = 0.f;
    #pragma unroll
    for (int j = 0; j < 64; ++j) s += abuf[t][j];
    atomicAdd(&Ssum[b * cK + t], s);
  }
}

// ---------------- GRU + LN + MLP residual ----------------
__global__ __launch_bounds__(128) void k_gru(const float* __restrict__ upd_raw, const float* __restrict__ Ssum,
    const float* __restrict__ ghs, const float* __restrict__ objsp,
    const float* __restrict__ w_ih, const float* __restrict__ b_ih,
    const float* __restrict__ mw1, const float* __restrict__ mb1,
    const float* __restrict__ mw2, const float* __restrict__ mb2,
    const float* __restrict__ ng_, const float* __restrict__ nb_,
    const float* __restrict__ lt,
    float* __restrict__ newobj, float* __restrict__ nsq,
    float* __restrict__ slots_out, int writeSlots){
  __shared__ float ubuf[cH], lbuf[cH], gbuf[cH], red[8];
  int bo = blockIdx.x; int b = bo >> 3, o = bo & 7;
  int t = threadIdx.x;
  int lane = t & 63, wid = t >> 6;

  float u = 0.f;
  #pragma unroll
  for (int l = 0; l < 3; ++l){
    int k = o * 3 + l;
    float s = Ssum[b * cK + k] + 1e-8f;
    u += upd_raw[((size_t)b * cK + k) * cH + t] / s;
  }
  ubuf[t] = u;
  __syncthreads();

  float gi[3];
  #pragma unroll
  for (int j3 = 0; j3 < 3; ++j3){
    const float* wr = w_ih + ((size_t)j3 * cH + t) * cH;
    float a0=0,a1=0,a2=0,a3=0;
    #pragma unroll
    for (int d = 0; d < cH; d += 4){
      a0 += wr[d]*ubuf[d]; a1 += wr[d+1]*ubuf[d+1]; a2 += wr[d+2]*ubuf[d+2]; a3 += wr[d+3]*ubuf[d+3];
    }
    gi[j3] = (a0+a1)+(a2+a3) + b_ih[j3 * cH + t];
  }
  const float* gh = ghs + (size_t)o * 3 * cH;
  float ghr = gh[t], ghz = gh[cH + t], ghn = gh[2 * cH + t];
  float oldv = objsp[(size_t)o * cH + t];
  float rg = 1.f / (1.f + expf(-(gi[0] + ghr)));
  float zg = 1.f / (1.f + expf(-(gi[1] + ghz)));
  float ngv = tanhf(gi[2] + rg * ghn);
  float nv = (1.f - zg) * ngv + zg * oldv;

  float s1 = nv, s2 = nv * nv;
  #pragma unroll
  for (int m = 1; m < 64; m <<= 1){ s1 += __shfl_xor(s1, m); s2 += __shfl_xor(s2, m); }
  if (lane == 0){ red[wid] = s1; red[4 + wid] = s2; }
  __syncthreads();
  float mean = (red[0] + red[1]) * (1.f/128.f);
  float var  = (red[4] + red[5]) * (1.f/128.f) - mean * mean;
  float ln = (nv - mean) * rsqrtf(var + 1e-5f) * ng_[t] + nb_[t];
  lbuf[t] = ln;
  __syncthreads();

  const float* w1r = mw1 + (size_t)t * cH;
  {
    float a0=0,a1=0,a2=0,a3=0;
    #pragma unroll
    for (int d = 0; d < cH; d += 4){
      a0 += w1r[d]*lbuf[d]; a1 += w1r[d+1]*lbuf[d+1]; a2 += w1r[d+2]*lbuf[d+2]; a3 += w1r[d+3]*lbuf[d+3];
    }
    gbuf[t] = gelu_f((a0+a1)+(a2+a3) + mb1[t]);
  }
  __syncthreads();
  const float* w2r = mw2 + (size_t)t * cH;
  float m2v;
  {
    float a0=0,a1=0,a2=0,a3=0;
    #pragma unroll
    for (int d = 0; d < cH; d += 4){
      a0 += w2r[d]*gbuf[d]; a1 += w2r[d+1]*gbuf[d+1]; a2 += w2r[d+2]*gbuf[d+2]; a3 += w2r[d+3]*gbuf[d+3];
    }
    m2v = (a0+a1)+(a2+a3) + mb2[t];
  }
  float outv = nv + 0.2f * m2v;
  newobj[((size_t)b * cO + o) * cH + t] = outv;

  float qv = outv * outv;
  #pragma unroll
  for (int m = 1; m < 64; m <<= 1) qv += __shfl_xor(qv, m);
  __syncthreads();
  if (lane == 0) red[wid] = qv;
  __syncthreads();
  if (t == 0) nsq[b * cO + o] = red[0] + red[1];

  if (writeSlots){
    #pragma unroll
    for (int l = 0; l < 3; ++l){
      size_t base = ((size_t)b * cK + o * 3 + l) * 129;
      slots_out[base + 1 + t] = outv;
      if (t == 0) slots_out[base] = lt[l];
    }
  }
}

extern "C" void kernel_launch(void* const* d_in, const int* in_sizes, int n_in,
                              void* d_out, int out_size, void* d_ws, size_t ws_size,
                              hipStream_t stream){
  const float* x       = (const float*)d_in[0];
  const float* enc_w1  = (const float*)d_in[1];
  const float* enc_b1  = (const float*)d_in[2];
  const float* enc_g1  = (const float*)d_in[3];
  const float* enc_bb1 = (const float*)d_in[4];
  const float* enc_w2  = (const float*)d_in[5];
  const float* enc_b2  = (const float*)d_in[6];
  const float* enc_g2  = (const float*)d_in[7];
  const float* enc_bb2 = (const float*)d_in[8];
  const float* sp_w1   = (const float*)d_in[9];
  const float* sp_b1   = (const float*)d_in[10];
  const float* sp_g    = (const float*)d_in[11];
  const float* sp_bb   = (const float*)d_in[12];
  const float* sp_w2   = (const float*)d_in[13];
  const float* sp_b2   = (const float*)d_in[14];
  const float* objsp   = (const float*)d_in[15];
  const float* hscale  = (const float*)d_in[16];
  const float* ltimes  = (const float*)d_in[17];
  const float* bhor    = (const float*)d_in[18];
  const float* gw_ih   = (const float*)d_in[19];
  const float* gw_hh   = (const float*)d_in[20];
  const float* gb_ih   = (const float*)d_in[21];
  const float* gb_hh   = (const float*)d_in[22];
  const float* mw1     = (const float*)d_in[23];
  const float* mb1     = (const float*)d_in[24];
  const float* mw2     = (const float*)d_in[25];
  const float* mb2     = (const float*)d_in[26];
  const float* normg   = (const float*)d_in[27];
  const float* normb   = (const float*)d_in[28];
  (void)in_sizes; (void)n_in; (void)out_size; (void)ws_size;

  float* out = (float*)d_out;
  float* ws  = (float*)d_ws;

  float* spatial = ws + WS_SPATIAL;
  float* sq      = ws + WS_SQ;
  float* ghs     = ws + WS_GHS;
  float* nsq0    = ws + WS_NSQ0;
  float* newobj  = ws + WS_NEWOBJ;
  float* nsqv    = ws + WS_NSQ;
  float* w1t     = ws + WS_W1T;
  float* w2t     = ws + WS_W2T;
  float* hw1t    = ws + WS_HW1T;
  float* updr3   = ws + WS_UPD3;
  float* Ss3     = ws + WS_S3;
  short* xbf     = (short*)(ws + WS_XBF);

  hipMemsetAsync((void*)updr3, 0, (size_t)(3 * cB * cK * cH + 3 * cB * cK) * sizeof(float), stream);

  k_cvt_sq<<<dim3(ROWS / 32), dim3(256), 0, stream>>>(x, xbf, sq);
  k_prep<<<dim3(175), dim3(256), 0, stream>>>(objsp, gw_hh, gb_hh, enc_w1, enc_w2, sp_w1,
                                              ghs, nsq0, w1t, w2t, hw1t);
  k_pairwise<<<dim3(cB * (cN / 16)), dim3(256), 0, stream>>>(xbf, sq, out + OUT_DEN);
  k_enc_head<<<dim3(ROWS / 16), dim3(256), 0, stream>>>(x, out + OUT_DEN,
      w1t, enc_b1, enc_g1, enc_bb1, w2t, enc_b2, enc_g2, enc_bb2,
      hw1t, sp_b1, sp_g, sp_bb, sp_w2, sp_b2,
      spatial, out + OUT_PT);

  for (int it = 0; it < 3; ++it){
    float* updr = updr3 + (size_t)it * cB * cK * cH;
    float* Ss   = Ss3 + (size_t)it * cB * cK;
    const float* objp = (it == 0) ? objsp : newobj;
    int obst = (it == 0) ? 0 : cO * cH;
    const float* nqp = (it == 0) ? nsq0 : nsqv;
    int nqst = (it == 0) ? 0 : cO;
    k_attn_upd<<<dim3(cB * 32), dim3(256), 0, stream>>>(spatial, out + OUT_PT, out + OUT_DEN,
                                                        objp, obst, nqp, nqst,
                                                        ltimes, bhor, hscale,
                                                        out + OUT_ATTN, (it == 2) ? 1 : 0,
                                                        updr, Ss);
    k_gru<<<dim3(cB * cO), dim3(128), 0, stream>>>(updr, Ss, ghs, objsp, gw_ih, gb_ih,
                                                   mw1, mb1, mw2, mb2, normg, normb, ltimes,
                                                   newobj, nsqv, out + OUT_SLOTS, (it == 2) ? 1 : 0);
  }
}

// Round 9
// 314.977 us; speedup vs baseline: 1.0809x; 1.0809x over previous
//
#include <hip/hip_runtime.h>
#include <math.h>

// ---- problem dims ----
constexpr int cB = 8, cN = 2048, cI = 64, cH = 128, cO = 8, cK = 24;
constexpr int ROWS = cB * cN; // 16384

// ---- ws layout (floats) ----
constexpr size_t WS_SPATIAL = 0;                                  // 16384*128
constexpr size_t WS_SQ      = WS_SPATIAL + (size_t)ROWS * cH;     // 16384
constexpr size_t WS_GHS     = WS_SQ + ROWS;                       // 8*384
constexpr size_t WS_NSQ0    = WS_GHS + (size_t)cO * 3 * cH;       // 8
constexpr size_t WS_NEWOBJ  = WS_NSQ0 + cO;                       // 8*8*128
constexpr size_t WS_NSQ     = WS_NEWOBJ + (size_t)cB * cO * cH;   // 64
constexpr size_t WS_WFRAG   = WS_NSQ + (size_t)cB * cO;           // 90112 shorts = 45056 floats
constexpr size_t WS_UPD3    = WS_WFRAG + 45056;                   // 3*8*24*128
constexpr size_t WS_S3      = WS_UPD3 + (size_t)3 * cB * cK * cH; // 3*8*24
constexpr size_t WS_XBF     = WS_S3 + (size_t)3 * cB * cK;        // 16384*64 bf16

// weight-fragment sub-offsets (in shorts, within WFRAG)
constexpr size_t WF_W1H = 0;        // 8*2*64*8  = 8192
constexpr size_t WF_W1L = 8192;
constexpr size_t WF_W2H = 16384;    // 8*4*64*8  = 16384
constexpr size_t WF_W2L = 32768;
constexpr size_t WF_WHH = 49152;    // 8*5*64*8  = 20480
constexpr size_t WF_WHL = 69632;    // total 90112

// ---- d_out layout (floats), return order: slots, attn, pred_time, density ----
constexpr size_t OUT_SLOTS = 0;
constexpr size_t OUT_ATTN  = (size_t)cB * cK * 129;
constexpr size_t OUT_PT    = OUT_ATTN + (size_t)cB * cK * cN;
constexpr size_t OUT_DEN   = OUT_PT + (size_t)cB * cN;

typedef __attribute__((ext_vector_type(8))) short bf16x8;
typedef __attribute__((ext_vector_type(4))) float f32x4;

__device__ __forceinline__ float gelu_f(float v){
  return 0.5f * v * (1.f + erff(v * 0.70710678118654752440f));
}
__device__ __forceinline__ short f2bf(float f){
  unsigned u = __float_as_uint(f);
  u += 0x7fffu + ((u >> 16) & 1u);   // RNE
  return (short)(u >> 16);
}
__device__ __forceinline__ float bf2f(short h){
  return __uint_as_float(((unsigned)(unsigned short)h) << 16);
}
__device__ __forceinline__ bf16x8 pack8(float4 a, float4 b){
  bf16x8 r;
  r[0]=f2bf(a.x); r[1]=f2bf(a.y); r[2]=f2bf(a.z); r[3]=f2bf(a.w);
  r[4]=f2bf(b.x); r[5]=f2bf(b.y); r[6]=f2bf(b.z); r[7]=f2bf(b.w);
  return r;
}
__device__ __forceinline__ float qred16(float a){  // sum over lane&15 group
  a += __shfl_xor(a, 1); a += __shfl_xor(a, 2); a += __shfl_xor(a, 4); a += __shfl_xor(a, 8);
  return a;
}
// f32 -> (hi,lo) bf16 split fragment from LDS (8 contiguous floats at off)
__device__ __forceinline__ void load_split_frag(const float* buf, int off, bf16x8& hi, bf16x8& lo){
  float4 u0 = *(const float4*)&buf[off];
  float4 u1 = *(const float4*)&buf[off + 4];
  float v[8] = {u0.x,u0.y,u0.z,u0.w,u1.x,u1.y,u1.z,u1.w};
  #pragma unroll
  for (int i = 0; i < 8; ++i){
    short h = f2bf(v[i]);
    hi[i] = h;
    lo[i] = f2bf(v[i] - bf2f(h));
  }
}
// swizzled LDS float-index: row*stride + (col ^ ((row&3)<<3))
__device__ __forceinline__ int lidx(int row, int col, int stride){
  return row * stride + (col ^ ((row & 3) << 3));
}

// ---------------- x -> bf16 copy (RNE) + sq = ||x||^2 ----------------
__global__ __launch_bounds__(256) void k_cvt_sq(const float* __restrict__ x, short* __restrict__ xbf,
                                                float* __restrict__ sq){
  int t = threadIdx.x;
  size_t base = (size_t)blockIdx.x * 2048;
  int r = t >> 3, e0 = (t & 7) * 8;
  const float4* xp = (const float4*)(x + base + (size_t)r * cI + e0);
  float4 v0 = xp[0], v1 = xp[1];
  *(bf16x8*)(xbf + base + (size_t)r * cI + e0) = pack8(v0, v1);
  float s = v0.x*v0.x + v0.y*v0.y + v0.z*v0.z + v0.w*v0.w
          + v1.x*v1.x + v1.y*v1.y + v1.z*v1.z + v1.w*v1.w;
  s += __shfl_xor(s, 1); s += __shfl_xor(s, 2); s += __shfl_xor(s, 4);
  if ((t & 7) == 0) sq[blockIdx.x * 32 + r] = s;
}

// ---------------- prep: ghs, ||obj||^2, split-bf16 weight fragments ----------------
// frag layout: arr[((ft*nc + c)*64 + lane)*8 + i] = W[ft*16 + (lane&15)][c*32 + (lane>>4)*8 + i]
__global__ __launch_bounds__(256) void k_prep(const float* __restrict__ objsp, const float* __restrict__ w_hh,
                                              const float* __restrict__ b_hh,
                                              const float* __restrict__ ew1, const float* __restrict__ ew2,
                                              const float* __restrict__ spw1,
                                              float* __restrict__ ghs, float* __restrict__ nsq0,
                                              short* __restrict__ wf){
  int id = blockIdx.x * 256 + threadIdx.x;
  if (id < cO * 3 * cH){
    int o = id / (3 * cH), j = id % (3 * cH);
    const float* wr = w_hh + (size_t)j * cH;
    const float* ob = objsp + (size_t)o * cH;
    float a0=0,a1=0,a2=0,a3=0;
    #pragma unroll
    for (int h = 0; h < cH; h += 4){
      a0 += wr[h]*ob[h]; a1 += wr[h+1]*ob[h+1]; a2 += wr[h+2]*ob[h+2]; a3 += wr[h+3]*ob[h+3];
    }
    ghs[id] = (a0+a1)+(a2+a3) + b_hh[j];
  } else if (id < cO * 3 * cH + cO){
    int o = id - cO * 3 * cH;
    const float* ob = objsp + (size_t)o * cH;
    float s = 0.f;
    for (int h = 0; h < cH; ++h) s += ob[h]*ob[h];
    nsq0[o] = s;
  } else {
    int idx = id - (cO * 3 * cH + cO);
    if (idx >= 45056) return;
    float w; size_t hoff, loff;
    int e, nc;
    if (idx < 8192){                 // W1: nc=2, K=64
      e = idx; nc = 2;
      int i = e & 7, l = (e >> 3) & 63, r = e >> 9;
      int c = r % nc, ft = r / nc;
      int f = ft * 16 + (l & 15), k = c * 32 + (l >> 4) * 8 + i;
      w = ew1[f * cI + k];
      hoff = WF_W1H + e; loff = WF_W1L + e;
    } else if (idx < 24576){         // W2: nc=4, K=128
      e = idx - 8192; nc = 4;
      int i = e & 7, l = (e >> 3) & 63, r = e >> 9;
      int c = r % nc, ft = r / nc;
      int f = ft * 16 + (l & 15), k = c * 32 + (l >> 4) * 8 + i;
      w = ew2[f * cH + k];
      hoff = WF_W2H + e; loff = WF_W2L + e;
    } else {                         // HW: nc=5, K=160 (k<129 real, else 0)
      e = idx - 24576; nc = 5;
      int i = e & 7, l = (e >> 3) & 63, r = e >> 9;
      int c = r % nc, ft = r / nc;
      int f = ft * 16 + (l & 15), k = c * 32 + (l >> 4) * 8 + i;
      w = (k < 129) ? spw1[f * 129 + k] : 0.f;
      hoff = WF_WHH + e; loff = WF_WHL + e;
    }
    short h = f2bf(w);
    wf[hoff] = h;
    wf[loff] = f2bf(w - bf2f(h));
  }
}

// ---------------- pairwise distances (bf16) + fused per-row top-6 -> density ----------------
__global__ __launch_bounds__(256) void k_pairwise(const short* __restrict__ xbf, const float* __restrict__ sq,
                                                  float* __restrict__ den_out){
  __shared__ float cand[4][16][101];
  int b  = blockIdx.x >> 7;
  int rt = blockIdx.x & 127;
  int r0 = rt * 16;
  int lane = threadIdx.x & 63, w = threadIdx.x >> 6;
  const short* xb = xbf + (size_t)b * cN * cI;

  int arow = r0 + (lane & 15);
  int koff = (lane >> 4) * 8;
  const bf16x8* ap = (const bf16x8*)(xb + (size_t)arow * cI + koff);
  bf16x8 a0 = ap[0];
  bf16x8 a1 = ap[4];

  float sqr[4];
  int rg0 = r0 + ((lane >> 4) << 2);
  #pragma unroll
  for (int j = 0; j < 4; ++j) sqr[j] = sq[b * cN + rg0 + j];

  float t6[4][6];
  #pragma unroll
  for (int j = 0; j < 4; ++j){
    #pragma unroll
    for (int q = 0; q < 6; ++q) t6[j][q] = 3e38f;
  }

  int cbase = w * 512;
  #pragma unroll 2
  for (int ct = 0; ct < 32; ++ct){
    int col0 = cbase + ct * 16;
    int brow = col0 + (lane & 15);
    const bf16x8* bp = (const bf16x8*)(xb + (size_t)brow * cI + koff);
    bf16x8 b0 = bp[0];
    bf16x8 b1 = bp[4];
    f32x4 acc = {0.f, 0.f, 0.f, 0.f};
    acc = __builtin_amdgcn_mfma_f32_16x16x32_bf16(a0, b0, acc, 0, 0, 0);
    acc = __builtin_amdgcn_mfma_f32_16x16x32_bf16(a1, b1, acc, 0, 0, 0);
    float sqc = sq[b * cN + col0 + (lane & 15)];
    #pragma unroll
    for (int j = 0; j < 4; ++j){
      float d2 = sqr[j] + sqc - 2.f * acc[j];
      d2 = fmaxf(d2, 0.f);
      if (d2 < t6[j][5]){
        if (d2 < t6[j][4]){ t6[j][5]=t6[j][4];
          if (d2 < t6[j][3]){ t6[j][4]=t6[j][3];
            if (d2 < t6[j][2]){ t6[j][3]=t6[j][2];
              if (d2 < t6[j][1]){ t6[j][2]=t6[j][1];
                if (d2 < t6[j][0]){ t6[j][1]=t6[j][0]; t6[j][0]=d2; } else t6[j][1]=d2;
              } else t6[j][2]=d2;
            } else t6[j][3]=d2;
          } else t6[j][4]=d2;
        } else t6[j][5]=d2;
      }
    }
  }
  int rloc = (lane >> 4) << 2;
  #pragma unroll
  for (int j = 0; j < 4; ++j){
    #pragma unroll
    for (int q = 0; q < 6; ++q) cand[w][rloc + j][(lane & 15) * 6 + q] = t6[j][q];
  }
  __syncthreads();
  int tt = threadIdx.x;
  if (tt < 64){
    int ww = tt >> 4, rr = tt & 15;
    const float* c = cand[ww][rr];
    float m0=3e38f,m1=3e38f,m2=3e38f,m3=3e38f,m4=3e38f,m5=3e38f;
    #pragma unroll
    for (int q = 0; q < 96; ++q){
      float v = c[q];
      if (v < m5){
        if (v<m4){ m5=m4; if (v<m3){ m4=m3; if (v<m2){ m3=m2; if (v<m1){ m2=m1; if (v<m0){ m1=m0; m0=v; } else m1=v; } else m2=v; } else m3=v; } else m4=v; } else m5=v;
      }
    }
    float* cw = cand[ww][rr];
    cw[0]=m0; cw[1]=m1; cw[2]=m2; cw[3]=m3; cw[4]=m4; cw[5]=m5;
  }
  __syncthreads();
  if (tt < 16){
    float m0=3e38f,m1=3e38f,m2=3e38f,m3=3e38f,m4=3e38f,m5=3e38f;
    #pragma unroll
    for (int ww = 0; ww < 4; ++ww){
      const float* c = cand[ww][tt];
      #pragma unroll
      for (int q = 0; q < 6; ++q){
        float v = c[q];
        if (v < m5){
          if (v<m4){ m5=m4; if (v<m3){ m4=m3; if (v<m2){ m3=m2; if (v<m1){ m2=m1; if (v<m0){ m1=m0; m0=v; } else m1=v; } else m2=v; } else m3=v; } else m4=v; } else m5=v;
        }
      }
    }
    float md = (sqrtf(m1)+sqrtf(m2)+sqrtf(m3)+sqrtf(m4)+sqrtf(m5)) * 0.2f;
    den_out[b * cN + r0 + tt] = tanhf(md);
  }
}

// ---------------- fused encoder + head via split-bf16 MFMA ----------------
// block = 128 thr = 2 waves; wave = 16 rows x 128 features. grid = ROWS/32 = 512.
__global__ __launch_bounds__(128) void k_enc_head(const float* __restrict__ x, const float* __restrict__ den_in,
    const short* __restrict__ wf,
    const float* __restrict__ b1, const float* __restrict__ g1, const float* __restrict__ bb1,
    const float* __restrict__ b2, const float* __restrict__ g2, const float* __restrict__ bb2,
    const float* __restrict__ hb1, const float* __restrict__ hg, const float* __restrict__ hbb,
    const float* __restrict__ hw2, const float* __restrict__ hb2,
    float* __restrict__ spatial, float* __restrict__ pt_out){
  __shared__ __align__(16) float xs_[2][16 * 68];
  __shared__ __align__(16) float hs_[2][16 * 164];
  const int t = threadIdx.x, lane = t & 63, wv = t >> 6;
  const int row0 = blockIdx.x * 32 + wv * 16;
  float* xbuf = xs_[wv];
  float* hbuf = hs_[wv];
  const int r15 = lane & 15, q = lane >> 4;
  const int qx = (q ^ (r15 & 3)) << 3;   // swizzled k-offset base for fragment reads

  // ---- stage 16 x-rows into swizzled LDS (coalesced) ----
  {
    const float4* xg = (const float4*)(x + (size_t)row0 * cI);
    #pragma unroll
    for (int k = 0; k < 4; ++k){
      int f4 = k * 64 + lane;               // 0..255
      int row = f4 >> 4, c4 = (f4 & 15) * 4;
      float4 v = xg[f4];
      *(float4*)&xbuf[lidx(row, c4, 68)] = v;
    }
  }
  __syncthreads();

  f32x4 acc[8];
  const short* w1h = wf + WF_W1H; const short* w1l = wf + WF_W1L;
  const short* w2h = wf + WF_W2H; const short* w2l = wf + WF_W2L;
  const short* whh = wf + WF_WHH; const short* whl = wf + WF_WHL;

  // ================= layer 1: K=64 (2 chunks) =================
  #pragma unroll
  for (int ft = 0; ft < 8; ++ft) acc[ft] = (f32x4){0.f,0.f,0.f,0.f};
  #pragma unroll
  for (int c = 0; c < 2; ++c){
    bf16x8 ah, al;
    load_split_frag(xbuf, r15 * 68 + c * 32 + qx, ah, al);
    #pragma unroll
    for (int ft = 0; ft < 8; ++ft){
      bf16x8 bh = *(const bf16x8*)&w1h[(size_t)(((ft*2 + c)*64) + lane) * 8];
      bf16x8 bl = *(const bf16x8*)&w1l[(size_t)(((ft*2 + c)*64) + lane) * 8];
      acc[ft] = __builtin_amdgcn_mfma_f32_16x16x32_bf16(al, bh, acc[ft], 0, 0, 0);
      acc[ft] = __builtin_amdgcn_mfma_f32_16x16x32_bf16(ah, bl, acc[ft], 0, 0, 0);
      acc[ft] = __builtin_amdgcn_mfma_f32_16x16x32_bf16(ah, bh, acc[ft], 0, 0, 0);
    }
  }
  { // LN + gelu -> hbuf
    float sm0=0,sm1=0,sm2=0,sm3=0, s20=0,s21=0,s22=0,s23=0;
    #pragma unroll
    for (int ft = 0; ft < 8; ++ft){
      float bv = b1[ft*16 + r15];
      float v0 = acc[ft][0]+bv, v1 = acc[ft][1]+bv, v2 = acc[ft][2]+bv, v3 = acc[ft][3]+bv;
      acc[ft][0]=v0; acc[ft][1]=v1; acc[ft][2]=v2; acc[ft][3]=v3;
      sm0+=v0; sm1+=v1; sm2+=v2; sm3+=v3;
      s20+=v0*v0; s21+=v1*v1; s22+=v2*v2; s23+=v3*v3;
    }
    sm0=qred16(sm0); sm1=qred16(sm1); sm2=qred16(sm2); sm3=qred16(sm3);
    s20=qred16(s20); s21=qred16(s21); s22=qred16(s22); s23=qred16(s23);
    float mean[4] = { sm0*(1.f/128.f), sm1*(1.f/128.f), sm2*(1.f/128.f), sm3*(1.f/128.f) };
    float rstd[4] = { rsqrtf(s20*(1.f/128.f)-mean[0]*mean[0]+1e-5f),
                      rsqrtf(s21*(1.f/128.f)-mean[1]*mean[1]+1e-5f),
                      rsqrtf(s22*(1.f/128.f)-mean[2]*mean[2]+1e-5f),
                      rsqrtf(s23*(1.f/128.f)-mean[3]*mean[3]+1e-5f) };
    #pragma unroll
    for (int ft = 0; ft < 8; ++ft){
      float gv = g1[ft*16 + r15], bbv = bb1[ft*16 + r15];
      #pragma unroll
      for (int j = 0; j < 4; ++j){
        float e = gelu_f((acc[ft][j]-mean[j])*rstd[j]*gv + bbv);
        hbuf[lidx(q*4 + j, ft*16 + r15, 164)] = e;
      }
    }
  }
  __syncthreads();

  // ================= layer 2: K=128 (4 chunks) =================
  #pragma unroll
  for (int ft = 0; ft < 8; ++ft) acc[ft] = (f32x4){0.f,0.f,0.f,0.f};
  #pragma unroll
  for (int c = 0; c < 4; ++c){
    bf16x8 ah, al;
    load_split_frag(hbuf, r15 * 164 + c * 32 + qx, ah, al);
    #pragma unroll
    for (int ft = 0; ft < 8; ++ft){
      bf16x8 bh = *(const bf16x8*)&w2h[(size_t)(((ft*4 + c)*64) + lane) * 8];
      bf16x8 bl = *(const bf16x8*)&w2l[(size_t)(((ft*4 + c)*64) + lane) * 8];
      acc[ft] = __builtin_amdgcn_mfma_f32_16x16x32_bf16(al, bh, acc[ft], 0, 0, 0);
      acc[ft] = __builtin_amdgcn_mfma_f32_16x16x32_bf16(ah, bl, acc[ft], 0, 0, 0);
      acc[ft] = __builtin_amdgcn_mfma_f32_16x16x32_bf16(ah, bh, acc[ft], 0, 0, 0);
    }
  }
  __syncthreads();   // all hbuf reads done before overwrite
  { // LN (no gelu) -> spatial values into hbuf cols 0..127 + den/zeros cols 128..159
    float sm0=0,sm1=0,sm2=0,sm3=0, s20=0,s21=0,s22=0,s23=0;
    #pragma unroll
    for (int ft = 0; ft < 8; ++ft){
      float bv = b2[ft*16 + r15];
      float v0 = acc[ft][0]+bv, v1 = acc[ft][1]+bv, v2 = acc[ft][2]+bv, v3 = acc[ft][3]+bv;
      acc[ft][0]=v0; acc[ft][1]=v1; acc[ft][2]=v2; acc[ft][3]=v3;
      sm0+=v0; sm1+=v1; sm2+=v2; sm3+=v3;
      s20+=v0*v0; s21+=v1*v1; s22+=v2*v2; s23+=v3*v3;
    }
    sm0=qred16(sm0); sm1=qred16(sm1); sm2=qred16(sm2); sm3=qred16(sm3);
    s20=qred16(s20); s21=qred16(s21); s22=qred16(s22); s23=qred16(s23);
    float mean[4] = { sm0*(1.f/128.f), sm1*(1.f/128.f), sm2*(1.f/128.f), sm3*(1.f/128.f) };
    float rstd[4] = { rsqrtf(s20*(1.f/128.f)-mean[0]*mean[0]+1e-5f),
                      rsqrtf(s21*(1.f/128.f)-mean[1]*mean[1]+1e-5f),
                      rsqrtf(s22*(1.f/128.f)-mean[2]*mean[2]+1e-5f),
                      rsqrtf(s23*(1.f/128.f)-mean[3]*mean[3]+1e-5f) };
    #pragma unroll
    for (int ft = 0; ft < 8; ++ft){
      float gv = g2[ft*16 + r15], bbv = bb2[ft*16 + r15];
      #pragma unroll
      for (int j = 0; j < 4; ++j){
        float s = (acc[ft][j]-mean[j])*rstd[j]*gv + bbv;
        hbuf[lidx(q*4 + j, ft*16 + r15, 164)] = s;
      }
    }
    // head-input tail: col 128 = den, 129..159 = 0
    #pragma unroll
    for (int i = 0; i < 8; ++i){
      int flat = lane * 8 + i;               // 0..511
      int row = flat >> 5, col = 128 + (flat & 31);
      float v = ((flat & 31) == 0) ? den_in[row0 + row] : 0.f;
      hbuf[lidx(row, col, 164)] = v;
    }
  }
  __syncthreads();

  // dump spatial (coalesced via LDS)
  {
    #pragma unroll
    for (int k = 0; k < 8; ++k){
      int f4 = k * 64 + lane;                // 0..511
      int row = f4 >> 5, c4 = (f4 & 31) * 4;
      float4 v = *(const float4*)&hbuf[lidx(row, c4, 164)];
      *(float4*)(spatial + (size_t)(row0 + row) * cH + c4) = v;
    }
  }

  // ================= head layer: K=160 (5 chunks) =================
  #pragma unroll
  for (int ft = 0; ft < 8; ++ft) acc[ft] = (f32x4){0.f,0.f,0.f,0.f};
  #pragma unroll
  for (int c = 0; c < 5; ++c){
    bf16x8 ah, al;
    load_split_frag(hbuf, r15 * 164 + c * 32 + qx, ah, al);
    #pragma unroll
    for (int ft = 0; ft < 8; ++ft){
      bf16x8 bh = *(const bf16x8*)&whh[(size_t)(((ft*5 + c)*64) + lane) * 8];
      bf16x8 bl = *(const bf16x8*)&whl[(size_t)(((ft*5 + c)*64) + lane) * 8];
      acc[ft] = __builtin_amdgcn_mfma_f32_16x16x32_bf16(al, bh, acc[ft], 0, 0, 0);
      acc[ft] = __builtin_amdgcn_mfma_f32_16x16x32_bf16(ah, bl, acc[ft], 0, 0, 0);
      acc[ft] = __builtin_amdgcn_mfma_f32_16x16x32_bf16(ah, bh, acc[ft], 0, 0, 0);
    }
  }
  { // LN + gelu + dot(hw2) + softplus -> pred_time
    float sm0=0,sm1=0,sm2=0,sm3=0, s20=0,s21=0,s22=0,s23=0;
    #pragma unroll
    for (int ft = 0; ft < 8; ++ft){
      float bv = hb1[ft*16 + r15];
      float v0 = acc[ft][0]+bv, v1 = acc[ft][1]+bv, v2 = acc[ft][2]+bv, v3 = acc[ft][3]+bv;
      acc[ft][0]=v0; acc[ft][1]=v1; acc[ft][2]=v2; acc[ft][3]=v3;
      sm0+=v0; sm1+=v1; sm2+=v2; sm3+=v3;
      s20+=v0*v0; s21+=v1*v1; s22+=v2*v2; s23+=v3*v3;
    }
    sm0=qred16(sm0); sm1=qred16(sm1); sm2=qred16(sm2); sm3=qred16(sm3);
    s20=qred16(s20); s21=qred16(s21); s22=qred16(s22); s23=qred16(s23);
    float mean[4] = { sm0*(1.f/128.f), sm1*(1.f/128.f), sm2*(1.f/128.f), sm3*(1.f/128.f) };
    float rstd[4] = { rsqrtf(s20*(1.f/128.f)-mean[0]*mean[0]+1e-5f),
                      rsqrtf(s21*(1.f/128.f)-mean[1]*mean[1]+1e-5f),
                      rsqrtf(s22*(1.f/128.f)-mean[2]*mean[2]+1e-5f),
                      rsqrtf(s23*(1.f/128.f)-mean[3]*mean[3]+1e-5f) };
    float part0=0, part1=0, part2=0, part3=0;
    #pragma unroll
    for (int ft = 0; ft < 8; ++ft){
      float gv = hg[ft*16 + r15], bbv = hbb[ft*16 + r15], w2v = hw2[ft*16 + r15];
      part0 += gelu_f((acc[ft][0]-mean[0])*rstd[0]*gv + bbv) * w2v;
      part1 += gelu_f((acc[ft][1]-mean[1])*rstd[1]*gv + bbv) * w2v;
      part2 += gelu_f((acc[ft][2]-mean[2])*rstd[2]*gv + bbv) * w2v;
      part3 += gelu_f((acc[ft][3]-mean[3])*rstd[3]*gv + bbv) * w2v;
    }
    part0=qred16(part0); part1=qred16(part1); part2=qred16(part2); part3=qred16(part3);
    float parts[4] = { part0, part1, part2, part3 };
    #pragma unroll
    for (int j = 0; j < 4; ++j){
      if (r15 == j){
        int row = q * 4 + j;
        float ps = parts[j] + hb2[0];
        float spl = fmaxf(ps, 0.f) + log1pf(expf(-fabsf(ps)));
        float dn = den_in[row0 + row];
        pt_out[row0 + row] = 5.f - 1.5f*dn + 0.5f*spl;
      }
    }
  }
}

// ---------------- fused attention + upd ----------------
__global__ __launch_bounds__(256) void k_attn_upd(const float* __restrict__ spatial, const float* __restrict__ pt_in,
    const float* __restrict__ den_in, const float* __restrict__ objp, int ob_stride,
    const float* __restrict__ nsqp, int nq_stride,
    const float* __restrict__ lt, const float* __restrict__ bh, const float* __restrict__ hs,
    float* __restrict__ attn_out, int writeAttn,
    float* __restrict__ upd_raw, float* __restrict__ Ssum){
  __shared__ float abuf[24][65];
  int blk = blockIdx.x;
  int b = blk >> 5, chunk = blk & 31;
  int n0 = chunk * 64;
  int t = threadIdx.x;
  int sub = t & 3, rl = t >> 2;
  int id = b * cN + n0 + rl;

  {
    float4 sv[8];
    const float4* sp4 = (const float4*)(spatial + (size_t)id * cH + sub * 32);
    #pragma unroll
    for (int i = 0; i < 8; ++i) sv[i] = sp4[i];
    float spn2 = 0.f;
    #pragma unroll
    for (int i = 0; i < 8; ++i) spn2 += sv[i].x*sv[i].x + sv[i].y*sv[i].y + sv[i].z*sv[i].z + sv[i].w*sv[i].w;

    const float* ob = objp + (size_t)b * ob_stride;
    float acc[8];
    #pragma unroll
    for (int o = 0; o < 8; ++o){
      const float4* orow = (const float4*)(ob + (size_t)o * cH + sub * 32);
      float a0=0,a1=0,a2=0,a3=0;
      #pragma unroll
      for (int i = 0; i < 8; ++i){ float4 w4 = orow[i];
        a0 += w4.x*sv[i].x; a1 += w4.y*sv[i].y; a2 += w4.z*sv[i].z; a3 += w4.w*sv[i].w; }
      acc[o] = (a0+a1)+(a2+a3);
    }
    spn2 += __shfl_xor(spn2, 1); spn2 += __shfl_xor(spn2, 2);
    #pragma unroll
    for (int o = 0; o < 8; ++o){ acc[o] += __shfl_xor(acc[o], 1); acc[o] += __shfl_xor(acc[o], 2); }

    if (sub == 0){
      const float* nq = nsqp + (size_t)b * nq_stride;
      float nsqv_[8];
      #pragma unroll
      for (int o = 0; o < 8; ++o) nsqv_[o] = nq[o];
      float pt = pt_in[id], den = den_in[id];
      float hsv = hs[0];
      float lts[3] = { lt[0], lt[1], lt[2] };
      float bhs[3] = { bh[0], bh[1], bh[2] };

      float logits[24];
      #pragma unroll
      for (int k = 0; k < 24; ++k){
        const int o = k / 3, l = k % 3;
        float dtv = pt - lts[l];
        float dr2 = fmaxf(spn2 + nsqv_[o] - 2.f * acc[o], 0.f);
        float ls  = dtv*dtv - dr2;
        float adL = sqrtf(fabsf(ls) + 1e-6f);
        float r   = sqrtf(dr2);
        float adt = fabsf(dtv);
        float hz  = fminf(fmaxf(bhs[l] + hsv * (den - 0.5f), 0.1f), 1.0f);
        float cone = hz - r / (adt + 1e-6f) - 10.f * fmaxf(-dtv, 0.f) - 5.f * fmaxf(r - adt, 0.f);
        logits[k] = (-adL + 0.5f * tanhf(cone)) * 10.f;
      }
      float mx = -3e38f;
      #pragma unroll
      for (int k = 0; k < 24; ++k) mx = fmaxf(mx, logits[k]);
      float es[24]; float ssum = 0.f;
      #pragma unroll
      for (int k = 0; k < 24; ++k){ es[k] = expf(logits[k] - mx); ssum += es[k]; }
      float inv = 1.f / ssum;
      #pragma unroll
      for (int k = 0; k < 24; ++k) abuf[k][rl] = es[k] * inv;
    }
  }
  __syncthreads();

  if (writeAttn){
    float* ao = attn_out + (size_t)b * cK * cN + n0;
    #pragma unroll
    for (int i = 0; i < 6; ++i){
      int idx = t + i * 256;
      ao[(size_t)(idx >> 6) * cN + (idx & 63)] = abuf[idx >> 6][idx & 63];
    }
  }

  int h = t & 127, g = t >> 7;
  float acc2[12];
  #pragma unroll
  for (int kk = 0; kk < 12; ++kk) acc2[kk] = 0.f;
  const float* sp = spatial + ((size_t)b * cN + n0) * cH + h;
  for (int ni = 0; ni < 64; ++ni){
    float spv = sp[(size_t)ni * cH];
    #pragma unroll
    for (int kk = 0; kk < 12; ++kk) acc2[kk] += abuf[g*12+kk][ni] * spv;
  }
  #pragma unroll
  for (int kk = 0; kk < 12; ++kk)
    atomicAdd(&upd_raw[((size_t)b * cK + g*12+kk) * cH + h], acc2[kk]);
  if (t < 24){
    float s = 0.f;
    #pragma unroll
    for (int j = 0; j < 64; ++j) s += abuf[t][j];
    atomicAdd(&Ssum[b * cK + t], s);
  }
}

// ---------------- GRU + LN + MLP residual ----------------
__global__ __launch_bounds__(128) void k_gru(const float* __restrict__ upd_raw, const float* __restrict__ Ssum,
    const float* __restrict__ ghs, const float* __restrict__ objsp,
    const float* __restrict__ w_ih, const float* __restrict__ b_ih,
    const float* __restrict__ mw1, const float* __restrict__ mb1,
    const float* __restrict__ mw2, const float* __restrict__ mb2,
    const float* __restrict__ ng_, const float* __restrict__ nb_,
    const float* __restrict__ lt,
    float* __restrict__ newobj, float* __restrict__ nsq,
    float* __restrict__ slots_out, int writeSlots){
  __shared__ float ubuf[cH], lbuf[cH], gbuf[cH], red[8];
  int bo = blockIdx.x; int b = bo >> 3, o = bo & 7;
  int t = threadIdx.x;
  int lane = t & 63, wid = t >> 6;

  float u = 0.f;
  #pragma unroll
  for (int l = 0; l < 3; ++l){
    int k = o * 3 + l;
    float s = Ssum[b * cK + k] + 1e-8f;
    u += upd_raw[((size_t)b * cK + k) * cH + t] / s;
  }
  ubuf[t] = u;
  __syncthreads();

  float gi[3];
  #pragma unroll
  for (int j3 = 0; j3 < 3; ++j3){
    const float* wr = w_ih + ((size_t)j3 * cH + t) * cH;
    float a0=0,a1=0,a2=0,a3=0;
    #pragma unroll
    for (int d = 0; d < cH; d += 4){
      a0 += wr[d]*ubuf[d]; a1 += wr[d+1]*ubuf[d+1]; a2 += wr[d+2]*ubuf[d+2]; a3 += wr[d+3]*ubuf[d+3];
    }
    gi[j3] = (a0+a1)+(a2+a3) + b_ih[j3 * cH + t];
  }
  const float* gh = ghs + (size_t)o * 3 * cH;
  float ghr = gh[t], ghz = gh[cH + t], ghn = gh[2 * cH + t];
  float oldv = objsp[(size_t)o * cH + t];
  float rg = 1.f / (1.f + expf(-(gi[0] + ghr)));
  float zg = 1.f / (1.f + expf(-(gi[1] + ghz)));
  float ngv = tanhf(gi[2] + rg * ghn);
  float nv = (1.f - zg) * ngv + zg * oldv;

  float s1 = nv, s2 = nv * nv;
  #pragma unroll
  for (int m = 1; m < 64; m <<= 1){ s1 += __shfl_xor(s1, m); s2 += __shfl_xor(s2, m); }
  if (lane == 0){ red[wid] = s1; red[4 + wid] = s2; }
  __syncthreads();
  float mean = (red[0] + red[1]) * (1.f/128.f);
  float var  = (red[4] + red[5]) * (1.f/128.f) - mean * mean;
  float ln = (nv - mean) * rsqrtf(var + 1e-5f) * ng_[t] + nb_[t];
  lbuf[t] = ln;
  __syncthreads();

  const float* w1r = mw1 + (size_t)t * cH;
  {
    float a0=0,a1=0,a2=0,a3=0;
    #pragma unroll
    for (int d = 0; d < cH; d += 4){
      a0 += w1r[d]*lbuf[d]; a1 += w1r[d+1]*lbuf[d+1]; a2 += w1r[d+2]*lbuf[d+2]; a3 += w1r[d+3]*lbuf[d+3];
    }
    gbuf[t] = gelu_f((a0+a1)+(a2+a3) + mb1[t]);
  }
  __syncthreads();
  const float* w2r = mw2 + (size_t)t * cH;
  float m2v;
  {
    float a0=0,a1=0,a2=0,a3=0;
    #pragma unroll
    for (int d = 0; d < cH; d += 4){
      a0 += w2r[d]*gbuf[d]; a1 += w2r[d+1]*gbuf[d+1]; a2 += w2r[d+2]*gbuf[d+2]; a3 += w2r[d+3]*gbuf[d+3];
    }
    m2v = (a0+a1)+(a2+a3) + mb2[t];
  }
  float outv = nv + 0.2f * m2v;
  newobj[((size_t)b * cO + o) * cH + t] = outv;

  float qv = outv * outv;
  #pragma unroll
  for (int m = 1; m < 64; m <<= 1) qv += __shfl_xor(qv, m);
  __syncthreads();
  if (lane == 0) red[wid] = qv;
  __syncthreads();
  if (t == 0) nsq[b * cO + o] = red[0] + red[1];

  if (writeSlots){
    #pragma unroll
    for (int l = 0; l < 3; ++l){
      size_t base = ((size_t)b * cK + o * 3 + l) * 129;
      slots_out[base + 1 + t] = outv;
      if (t == 0) slots_out[base] = lt[l];
    }
  }
}

extern "C" void kernel_launch(void* const* d_in, const int* in_sizes, int n_in,
                              void* d_out, int out_size, void* d_ws, size_t ws_size,
                              hipStream_t stream){
  const float* x       = (const float*)d_in[0];
  const float* enc_w1  = (const float*)d_in[1];
  const float* enc_b1  = (const float*)d_in[2];
  const float* enc_g1  = (const float*)d_in[3];
  const float* enc_bb1 = (const float*)d_in[4];
  const float* enc_w2  = (const float*)d_in[5];
  const float* enc_b2  = (const float*)d_in[6];
  const float* enc_g2  = (const float*)d_in[7];
  const float* enc_bb2 = (const float*)d_in[8];
  const float* sp_w1   = (const float*)d_in[9];
  const float* sp_b1   = (const float*)d_in[10];
  const float* sp_g    = (const float*)d_in[11];
  const float* sp_bb   = (const float*)d_in[12];
  const float* sp_w2   = (const float*)d_in[13];
  const float* sp_b2   = (const float*)d_in[14];
  const float* objsp   = (const float*)d_in[15];
  const float* hscale  = (const float*)d_in[16];
  const float* ltimes  = (const float*)d_in[17];
  const float* bhor    = (const float*)d_in[18];
  const float* gw_ih   = (const float*)d_in[19];
  const float* gw_hh   = (const float*)d_in[20];
  const float* gb_ih   = (const float*)d_in[21];
  const float* gb_hh   = (const float*)d_in[22];
  const float* mw1     = (const float*)d_in[23];
  const float* mb1     = (const float*)d_in[24];
  const float* mw2     = (const float*)d_in[25];
  const float* mb2     = (const float*)d_in[26];
  const float* normg   = (const float*)d_in[27];
  const float* normb   = (const float*)d_in[28];
  (void)in_sizes; (void)n_in; (void)out_size; (void)ws_size;

  float* out = (float*)d_out;
  float* ws  = (float*)d_ws;

  float* spatial = ws + WS_SPATIAL;
  float* sq      = ws + WS_SQ;
  float* ghs     = ws + WS_GHS;
  float* nsq0    = ws + WS_NSQ0;
  float* newobj  = ws + WS_NEWOBJ;
  float* nsqv    = ws + WS_NSQ;
  short* wf      = (short*)(ws + WS_WFRAG);
  float* updr3   = ws + WS_UPD3;
  float* Ss3     = ws + WS_S3;
  short* xbf     = (short*)(ws + WS_XBF);

  hipMemsetAsync((void*)updr3, 0, (size_t)(3 * cB * cK * cH + 3 * cB * cK) * sizeof(float), stream);

  k_cvt_sq<<<dim3(ROWS / 32), dim3(256), 0, stream>>>(x, xbf, sq);
  k_prep<<<dim3(189), dim3(256), 0, stream>>>(objsp, gw_hh, gb_hh, enc_w1, enc_w2, sp_w1,
                                              ghs, nsq0, wf);
  k_pairwise<<<dim3(cB * (cN / 16)), dim3(256), 0, stream>>>(xbf, sq, out + OUT_DEN);
  k_enc_head<<<dim3(ROWS / 32), dim3(128), 0, stream>>>(x, out + OUT_DEN, wf,
      enc_b1, enc_g1, enc_bb1, enc_b2, enc_g2, enc_bb2,
      sp_b1, sp_g, sp_bb, sp_w2, sp_b2,
      spatial, out + OUT_PT);

  for (int it = 0; it < 3; ++it){
    float* updr = updr3 + (size_t)it * cB * cK * cH;
    float* Ss   = Ss3 + (size_t)it * cB * cK;
    const float* objp = (it == 0) ? objsp : newobj;
    int obst = (it == 0) ? 0 : cO * cH;
    const float* nqp = (it == 0) ? nsq0 : nsqv;
    int nqst = (it == 0) ? 0 : cO;
    k_attn_upd<<<dim3(cB * 32), dim3(256), 0, stream>>>(spatial, out + OUT_PT, out + OUT_DEN,
                                                        objp, obst, nqp, nqst,
                                                        ltimes, bhor, hscale,
                                                        out + OUT_ATTN, (it == 2) ? 1 : 0,
                                                        updr, Ss);
    k_gru<<<dim3(cB * cO), dim3(128), 0, stream>>>(updr, Ss, ghs, objsp, gw_ih, gb_ih,
                                                   mw1, mb1, mw2, mb2, normg, normb, ltimes,
                                                   newobj, nsqv, out + OUT_SLOTS, (it == 2) ? 1 : 0);
  }
}

// Round 10
// 303.288 us; speedup vs baseline: 1.1226x; 1.0385x over previous
//
#include <hip/hip_runtime.h>
#include <math.h>

// ---- problem dims ----
constexpr int cB = 8, cN = 2048, cI = 64, cH = 128, cO = 8, cK = 24;
constexpr int ROWS = cB * cN; // 16384

// ---- ws layout (floats) ----
constexpr size_t WS_SPATIAL = 0;                                  // 16384*128
constexpr size_t WS_SQ      = WS_SPATIAL + (size_t)ROWS * cH;     // 16384
constexpr size_t WS_GHS     = WS_SQ + ROWS;                       // 8*384
constexpr size_t WS_NSQ0    = WS_GHS + (size_t)cO * 3 * cH;       // 8
constexpr size_t WS_NEWOBJ  = WS_NSQ0 + cO;                       // 8*8*128
constexpr size_t WS_NSQ     = WS_NEWOBJ + (size_t)cB * cO * cH;   // 64
constexpr size_t WS_WFRAG   = WS_NSQ + (size_t)cB * cO;           // 90112 shorts = 45056 floats
constexpr size_t WS_UPD3    = WS_WFRAG + 45056;                   // 3*8*24*128
constexpr size_t WS_S3      = WS_UPD3 + (size_t)3 * cB * cK * cH; // 3*8*24
constexpr size_t WS_XBF     = WS_S3 + (size_t)3 * cB * cK;        // 16384*64 bf16

// weight-fragment sub-offsets (in shorts, within WFRAG)
constexpr size_t WF_W1H = 0;        // 8*2*64*8  = 8192
constexpr size_t WF_W1L = 8192;
constexpr size_t WF_W2H = 16384;    // 8*4*64*8  = 16384
constexpr size_t WF_W2L = 32768;
constexpr size_t WF_WHH = 49152;    // 8*5*64*8  = 20480
constexpr size_t WF_WHL = 69632;    // total 90112

// ---- d_out layout (floats), return order: slots, attn, pred_time, density ----
constexpr size_t OUT_SLOTS = 0;
constexpr size_t OUT_ATTN  = (size_t)cB * cK * 129;
constexpr size_t OUT_PT    = OUT_ATTN + (size_t)cB * cK * cN;
constexpr size_t OUT_DEN   = OUT_PT + (size_t)cB * cN;

typedef __attribute__((ext_vector_type(8))) short bf16x8;
typedef __attribute__((ext_vector_type(4))) float f32x4;

__device__ __forceinline__ float gelu_f(float v){
  return 0.5f * v * (1.f + erff(v * 0.70710678118654752440f));
}
__device__ __forceinline__ short f2bf(float f){
  unsigned u = __float_as_uint(f);
  u += 0x7fffu + ((u >> 16) & 1u);   // RNE
  return (short)(u >> 16);
}
__device__ __forceinline__ float bf2f(short h){
  return __uint_as_float(((unsigned)(unsigned short)h) << 16);
}
__device__ __forceinline__ bf16x8 pack8(float4 a, float4 b){
  bf16x8 r;
  r[0]=f2bf(a.x); r[1]=f2bf(a.y); r[2]=f2bf(a.z); r[3]=f2bf(a.w);
  r[4]=f2bf(b.x); r[5]=f2bf(b.y); r[6]=f2bf(b.z); r[7]=f2bf(b.w);
  return r;
}
__device__ __forceinline__ float qred16(float a){  // sum over lane&15 group
  a += __shfl_xor(a, 1); a += __shfl_xor(a, 2); a += __shfl_xor(a, 4); a += __shfl_xor(a, 8);
  return a;
}
// branchless sorted-insert of x into ascending 6-vector (keep 6 smallest):
// t0'=min(t0,x); tk'=med3(t(k-1),tk,x)  [1 v_min + 5 v_med3]
#define INS6(T0,T1,T2,T3,T4,T5,X) { \
  float _o0=T0,_o1=T1,_o2=T2,_o3=T3,_o4=T4,_o5=T5; \
  T0 = fminf(_o0, X); \
  T1 = __builtin_amdgcn_fmed3f(_o0,_o1,X); \
  T2 = __builtin_amdgcn_fmed3f(_o1,_o2,X); \
  T3 = __builtin_amdgcn_fmed3f(_o2,_o3,X); \
  T4 = __builtin_amdgcn_fmed3f(_o3,_o4,X); \
  T5 = __builtin_amdgcn_fmed3f(_o4,_o5,X); \
}
// f32 -> (hi,lo) bf16 split fragment from LDS (8 contiguous floats at off)
__device__ __forceinline__ void load_split_frag(const float* buf, int off, bf16x8& hi, bf16x8& lo){
  float4 u0 = *(const float4*)&buf[off];
  float4 u1 = *(const float4*)&buf[off + 4];
  float v[8] = {u0.x,u0.y,u0.z,u0.w,u1.x,u1.y,u1.z,u1.w};
  #pragma unroll
  for (int i = 0; i < 8; ++i){
    short h = f2bf(v[i]);
    hi[i] = h;
    lo[i] = f2bf(v[i] - bf2f(h));
  }
}
// swizzled LDS float-index: row*stride + (col ^ ((row&3)<<3))
__device__ __forceinline__ int lidx(int row, int col, int stride){
  return row * stride + (col ^ ((row & 3) << 3));
}

// ---------------- x -> bf16 copy (RNE) + sq = ||x||^2 ----------------
__global__ __launch_bounds__(256) void k_cvt_sq(const float* __restrict__ x, short* __restrict__ xbf,
                                                float* __restrict__ sq){
  int t = threadIdx.x;
  size_t base = (size_t)blockIdx.x * 2048;
  int r = t >> 3, e0 = (t & 7) * 8;
  const float4* xp = (const float4*)(x + base + (size_t)r * cI + e0);
  float4 v0 = xp[0], v1 = xp[1];
  *(bf16x8*)(xbf + base + (size_t)r * cI + e0) = pack8(v0, v1);
  float s = v0.x*v0.x + v0.y*v0.y + v0.z*v0.z + v0.w*v0.w
          + v1.x*v1.x + v1.y*v1.y + v1.z*v1.z + v1.w*v1.w;
  s += __shfl_xor(s, 1); s += __shfl_xor(s, 2); s += __shfl_xor(s, 4);
  if ((t & 7) == 0) sq[blockIdx.x * 32 + r] = s;
}

// ---------------- prep: ghs, ||obj||^2, split-bf16 weight fragments ----------------
// frag layout: arr[((ft*nc + c)*64 + lane)*8 + i] = W[ft*16 + (lane&15)][c*32 + (lane>>4)*8 + i]
__global__ __launch_bounds__(256) void k_prep(const float* __restrict__ objsp, const float* __restrict__ w_hh,
                                              const float* __restrict__ b_hh,
                                              const float* __restrict__ ew1, const float* __restrict__ ew2,
                                              const float* __restrict__ spw1,
                                              float* __restrict__ ghs, float* __restrict__ nsq0,
                                              short* __restrict__ wf){
  int id = blockIdx.x * 256 + threadIdx.x;
  if (id < cO * 3 * cH){
    int o = id / (3 * cH), j = id % (3 * cH);
    const float* wr = w_hh + (size_t)j * cH;
    const float* ob = objsp + (size_t)o * cH;
    float a0=0,a1=0,a2=0,a3=0;
    #pragma unroll
    for (int h = 0; h < cH; h += 4){
      a0 += wr[h]*ob[h]; a1 += wr[h+1]*ob[h+1]; a2 += wr[h+2]*ob[h+2]; a3 += wr[h+3]*ob[h+3];
    }
    ghs[id] = (a0+a1)+(a2+a3) + b_hh[j];
  } else if (id < cO * 3 * cH + cO){
    int o = id - cO * 3 * cH;
    const float* ob = objsp + (size_t)o * cH;
    float s = 0.f;
    for (int h = 0; h < cH; ++h) s += ob[h]*ob[h];
    nsq0[o] = s;
  } else {
    int idx = id - (cO * 3 * cH + cO);
    if (idx >= 45056) return;
    float w; size_t hoff, loff;
    int e, nc;
    if (idx < 8192){                 // W1: nc=2, K=64
      e = idx; nc = 2;
      int i = e & 7, l = (e >> 3) & 63, r = e >> 9;
      int c = r % nc, ft = r / nc;
      int f = ft * 16 + (l & 15), k = c * 32 + (l >> 4) * 8 + i;
      w = ew1[f * cI + k];
      hoff = WF_W1H + e; loff = WF_W1L + e;
    } else if (idx < 24576){         // W2: nc=4, K=128
      e = idx - 8192; nc = 4;
      int i = e & 7, l = (e >> 3) & 63, r = e >> 9;
      int c = r % nc, ft = r / nc;
      int f = ft * 16 + (l & 15), k = c * 32 + (l >> 4) * 8 + i;
      w = ew2[f * cH + k];
      hoff = WF_W2H + e; loff = WF_W2L + e;
    } else {                         // HW: nc=5, K=160 (k<129 real, else 0)
      e = idx - 24576; nc = 5;
      int i = e & 7, l = (e >> 3) & 63, r = e >> 9;
      int c = r % nc, ft = r / nc;
      int f = ft * 16 + (l & 15), k = c * 32 + (l >> 4) * 8 + i;
      w = (k < 129) ? spw1[f * 129 + k] : 0.f;
      hoff = WF_WHH + e; loff = WF_WHL + e;
    }
    short h = f2bf(w);
    wf[hoff] = h;
    wf[loff] = f2bf(w - bf2f(h));
  }
}

// ---------------- pairwise distances (bf16) + fused per-row top-6 -> density ----------------
__global__ __launch_bounds__(256) void k_pairwise(const short* __restrict__ xbf, const float* __restrict__ sq,
                                                  float* __restrict__ den_out){
  __shared__ float cand[4][16][101];
  int b  = blockIdx.x >> 7;
  int rt = blockIdx.x & 127;
  int r0 = rt * 16;
  int lane = threadIdx.x & 63, w = threadIdx.x >> 6;
  const short* xb = xbf + (size_t)b * cN * cI;

  int arow = r0 + (lane & 15);
  int koff = (lane >> 4) * 8;
  const bf16x8* ap = (const bf16x8*)(xb + (size_t)arow * cI + koff);
  bf16x8 a0 = ap[0];
  bf16x8 a1 = ap[4];

  float sqr[4];
  int rg0 = r0 + ((lane >> 4) << 2);
  #pragma unroll
  for (int j = 0; j < 4; ++j) sqr[j] = sq[b * cN + rg0 + j];

  float t6[4][6];
  #pragma unroll
  for (int j = 0; j < 4; ++j){
    #pragma unroll
    for (int q = 0; q < 6; ++q) t6[j][q] = 3e38f;
  }

  int cbase = w * 512;
  #pragma unroll 2
  for (int ct = 0; ct < 32; ++ct){
    int col0 = cbase + ct * 16;
    int brow = col0 + (lane & 15);
    const bf16x8* bp = (const bf16x8*)(xb + (size_t)brow * cI + koff);
    bf16x8 b0 = bp[0];
    bf16x8 b1 = bp[4];
    f32x4 acc = {0.f, 0.f, 0.f, 0.f};
    acc = __builtin_amdgcn_mfma_f32_16x16x32_bf16(a0, b0, acc, 0, 0, 0);
    acc = __builtin_amdgcn_mfma_f32_16x16x32_bf16(a1, b1, acc, 0, 0, 0);
    float sqc = sq[b * cN + col0 + (lane & 15)];
    #pragma unroll
    for (int j = 0; j < 4; ++j){
      float d2 = sqr[j] + sqc - 2.f * acc[j];
      d2 = fmaxf(d2, 0.f);
      INS6(t6[j][0], t6[j][1], t6[j][2], t6[j][3], t6[j][4], t6[j][5], d2);
    }
  }
  int rloc = (lane >> 4) << 2;
  #pragma unroll
  for (int j = 0; j < 4; ++j){
    #pragma unroll
    for (int q = 0; q < 6; ++q) cand[w][rloc + j][(lane & 15) * 6 + q] = t6[j][q];
  }
  __syncthreads();
  int tt = threadIdx.x;
  if (tt < 64){
    int ww = tt >> 4, rr = tt & 15;
    const float* c = cand[ww][rr];
    float m0=3e38f,m1=3e38f,m2=3e38f,m3=3e38f,m4=3e38f,m5=3e38f;
    #pragma unroll
    for (int q = 0; q < 96; ++q){
      float v = c[q];
      INS6(m0, m1, m2, m3, m4, m5, v);
    }
    float* cw = cand[ww][rr];
    cw[0]=m0; cw[1]=m1; cw[2]=m2; cw[3]=m3; cw[4]=m4; cw[5]=m5;
  }
  __syncthreads();
  if (tt < 16){
    float m0=3e38f,m1=3e38f,m2=3e38f,m3=3e38f,m4=3e38f,m5=3e38f;
    #pragma unroll
    for (int ww = 0; ww < 4; ++ww){
      const float* c = cand[ww][tt];
      #pragma unroll
      for (int q = 0; q < 6; ++q){
        float v = c[q];
        INS6(m0, m1, m2, m3, m4, m5, v);
      }
    }
    float md = (sqrtf(m1)+sqrtf(m2)+sqrtf(m3)+sqrtf(m4)+sqrtf(m5)) * 0.2f;
    den_out[b * cN + r0 + tt] = tanhf(md);
  }
}

// ---------------- fused encoder + head via split-bf16 MFMA ----------------
// block = 128 thr = 2 waves; wave = 16 rows x 128 features. grid = ROWS/32 = 512.
__global__ __launch_bounds__(128) void k_enc_head(const float* __restrict__ x, const float* __restrict__ den_in,
    const short* __restrict__ wf,
    const float* __restrict__ b1, const float* __restrict__ g1, const float* __restrict__ bb1,
    const float* __restrict__ b2, const float* __restrict__ g2, const float* __restrict__ bb2,
    const float* __restrict__ hb1, const float* __restrict__ hg, const float* __restrict__ hbb,
    const float* __restrict__ hw2, const float* __restrict__ hb2,
    float* __restrict__ spatial, float* __restrict__ pt_out){
  __shared__ __align__(16) float xs_[2][16 * 68];
  __shared__ __align__(16) float hs_[2][16 * 164];
  const int t = threadIdx.x, lane = t & 63, wv = t >> 6;
  const int row0 = blockIdx.x * 32 + wv * 16;
  float* xbuf = xs_[wv];
  float* hbuf = hs_[wv];
  const int r15 = lane & 15, q = lane >> 4;
  const int qx = (q ^ (r15 & 3)) << 3;   // swizzled k-offset base for fragment reads

  // ---- stage 16 x-rows into swizzled LDS (coalesced) ----
  {
    const float4* xg = (const float4*)(x + (size_t)row0 * cI);
    #pragma unroll
    for (int k = 0; k < 4; ++k){
      int f4 = k * 64 + lane;               // 0..255
      int row = f4 >> 4, c4 = (f4 & 15) * 4;
      float4 v = xg[f4];
      *(float4*)&xbuf[lidx(row, c4, 68)] = v;
    }
  }
  __syncthreads();

  f32x4 acc[8];
  const short* w1h = wf + WF_W1H; const short* w1l = wf + WF_W1L;
  const short* w2h = wf + WF_W2H; const short* w2l = wf + WF_W2L;
  const short* whh = wf + WF_WHH; const short* whl = wf + WF_WHL;

  // ================= layer 1: K=64 (2 chunks) =================
  #pragma unroll
  for (int ft = 0; ft < 8; ++ft) acc[ft] = (f32x4){0.f,0.f,0.f,0.f};
  #pragma unroll
  for (int c = 0; c < 2; ++c){
    bf16x8 ah, al;
    load_split_frag(xbuf, r15 * 68 + c * 32 + qx, ah, al);
    #pragma unroll
    for (int ft = 0; ft < 8; ++ft){
      bf16x8 bh = *(const bf16x8*)&w1h[(size_t)(((ft*2 + c)*64) + lane) * 8];
      bf16x8 bl = *(const bf16x8*)&w1l[(size_t)(((ft*2 + c)*64) + lane) * 8];
      acc[ft] = __builtin_amdgcn_mfma_f32_16x16x32_bf16(al, bh, acc[ft], 0, 0, 0);
      acc[ft] = __builtin_amdgcn_mfma_f32_16x16x32_bf16(ah, bl, acc[ft], 0, 0, 0);
      acc[ft] = __builtin_amdgcn_mfma_f32_16x16x32_bf16(ah, bh, acc[ft], 0, 0, 0);
    }
  }
  { // LN + gelu -> hbuf
    float sm0=0,sm1=0,sm2=0,sm3=0, s20=0,s21=0,s22=0,s23=0;
    #pragma unroll
    for (int ft = 0; ft < 8; ++ft){
      float bv = b1[ft*16 + r15];
      float v0 = acc[ft][0]+bv, v1 = acc[ft][1]+bv, v2 = acc[ft][2]+bv, v3 = acc[ft][3]+bv;
      acc[ft][0]=v0; acc[ft][1]=v1; acc[ft][2]=v2; acc[ft][3]=v3;
      sm0+=v0; sm1+=v1; sm2+=v2; sm3+=v3;
      s20+=v0*v0; s21+=v1*v1; s22+=v2*v2; s23+=v3*v3;
    }
    sm0=qred16(sm0); sm1=qred16(sm1); sm2=qred16(sm2); sm3=qred16(sm3);
    s20=qred16(s20); s21=qred16(s21); s22=qred16(s22); s23=qred16(s23);
    float mean[4] = { sm0*(1.f/128.f), sm1*(1.f/128.f), sm2*(1.f/128.f), sm3*(1.f/128.f) };
    float rstd[4] = { rsqrtf(s20*(1.f/128.f)-mean[0]*mean[0]+1e-5f),
                      rsqrtf(s21*(1.f/128.f)-mean[1]*mean[1]+1e-5f),
                      rsqrtf(s22*(1.f/128.f)-mean[2]*mean[2]+1e-5f),
                      rsqrtf(s23*(1.f/128.f)-mean[3]*mean[3]+1e-5f) };
    #pragma unroll
    for (int ft = 0; ft < 8; ++ft){
      float gv = g1[ft*16 + r15], bbv = bb1[ft*16 + r15];
      #pragma unroll
      for (int j = 0; j < 4; ++j){
        float e = gelu_f((acc[ft][j]-mean[j])*rstd[j]*gv + bbv);
        hbuf[lidx(q*4 + j, ft*16 + r15, 164)] = e;
      }
    }
  }
  __syncthreads();

  // ================= layer 2: K=128 (4 chunks) =================
  #pragma unroll
  for (int ft = 0; ft < 8; ++ft) acc[ft] = (f32x4){0.f,0.f,0.f,0.f};
  #pragma unroll
  for (int c = 0; c < 4; ++c){
    bf16x8 ah, al;
    load_split_frag(hbuf, r15 * 164 + c * 32 + qx, ah, al);
    #pragma unroll
    for (int ft = 0; ft < 8; ++ft){
      bf16x8 bh = *(const bf16x8*)&w2h[(size_t)(((ft*4 + c)*64) + lane) * 8];
      bf16x8 bl = *(const bf16x8*)&w2l[(size_t)(((ft*4 + c)*64) + lane) * 8];
      acc[ft] = __builtin_amdgcn_mfma_f32_16x16x32_bf16(al, bh, acc[ft], 0, 0, 0);
      acc[ft] = __builtin_amdgcn_mfma_f32_16x16x32_bf16(ah, bl, acc[ft], 0, 0, 0);
      acc[ft] = __builtin_amdgcn_mfma_f32_16x16x32_bf16(ah, bh, acc[ft], 0, 0, 0);
    }
  }
  __syncthreads();   // all hbuf reads done before overwrite
  { // LN (no gelu) -> spatial values into hbuf cols 0..127 + den/zeros cols 128..159
    float sm0=0,sm1=0,sm2=0,sm3=0, s20=0,s21=0,s22=0,s23=0;
    #pragma unroll
    for (int ft = 0; ft < 8; ++ft){
      float bv = b2[ft*16 + r15];
      float v0 = acc[ft][0]+bv, v1 = acc[ft][1]+bv, v2 = acc[ft][2]+bv, v3 = acc[ft][3]+bv;
      acc[ft][0]=v0; acc[ft][1]=v1; acc[ft][2]=v2; acc[ft][3]=v3;
      sm0+=v0; sm1+=v1; sm2+=v2; sm3+=v3;
      s20+=v0*v0; s21+=v1*v1; s22+=v2*v2; s23+=v3*v3;
    }
    sm0=qred16(sm0); sm1=qred16(sm1); sm2=qred16(sm2); sm3=qred16(sm3);
    s20=qred16(s20); s21=qred16(s21); s22=qred16(s22); s23=qred16(s23);
    float mean[4] = { sm0*(1.f/128.f), sm1*(1.f/128.f), sm2*(1.f/128.f), sm3*(1.f/128.f) };
    float rstd[4] = { rsqrtf(s20*(1.f/128.f)-mean[0]*mean[0]+1e-5f),
                      rsqrtf(s21*(1.f/128.f)-mean[1]*mean[1]+1e-5f),
                      rsqrtf(s22*(1.f/128.f)-mean[2]*mean[2]+1e-5f),
                      rsqrtf(s23*(1.f/128.f)-mean[3]*mean[3]+1e-5f) };
    #pragma unroll
    for (int ft = 0; ft < 8; ++ft){
      float gv = g2[ft*16 + r15], bbv = bb2[ft*16 + r15];
      #pragma unroll
      for (int j = 0; j < 4; ++j){
        float s = (acc[ft][j]-mean[j])*rstd[j]*gv + bbv;
        hbuf[lidx(q*4 + j, ft*16 + r15, 164)] = s;
      }
    }
    // head-input tail: col 128 = den, 129..159 = 0
    #pragma unroll
    for (int i = 0; i < 8; ++i){
      int flat = lane * 8 + i;               // 0..511
      int row = flat >> 5, col = 128 + (flat & 31);
      float v = ((flat & 31) == 0) ? den_in[row0 + row] : 0.f;
      hbuf[lidx(row, col, 164)] = v;
    }
  }
  __syncthreads();

  // dump spatial (coalesced via LDS)
  {
    #pragma unroll
    for (int k = 0; k < 8; ++k){
      int f4 = k * 64 + lane;                // 0..511
      int row = f4 >> 5, c4 = (f4 & 31) * 4;
      float4 v = *(const float4*)&hbuf[lidx(row, c4, 164)];
      *(float4*)(spatial + (size_t)(row0 + row) * cH + c4) = v;
    }
  }

  // ================= head layer: K=160 (5 chunks) =================
  #pragma unroll
  for (int ft = 0; ft < 8; ++ft) acc[ft] = (f32x4){0.f,0.f,0.f,0.f};
  #pragma unroll
  for (int c = 0; c < 5; ++c){
    bf16x8 ah, al;
    load_split_frag(hbuf, r15 * 164 + c * 32 + qx, ah, al);
    #pragma unroll
    for (int ft = 0; ft < 8; ++ft){
      bf16x8 bh = *(const bf16x8*)&whh[(size_t)(((ft*5 + c)*64) + lane) * 8];
      bf16x8 bl = *(const bf16x8*)&whl[(size_t)(((ft*5 + c)*64) + lane) * 8];
      acc[ft] = __builtin_amdgcn_mfma_f32_16x16x32_bf16(al, bh, acc[ft], 0, 0, 0);
      acc[ft] = __builtin_amdgcn_mfma_f32_16x16x32_bf16(ah, bl, acc[ft], 0, 0, 0);
      acc[ft] = __builtin_amdgcn_mfma_f32_16x16x32_bf16(ah, bh, acc[ft], 0, 0, 0);
    }
  }
  { // LN + gelu + dot(hw2) + softplus -> pred_time
    float sm0=0,sm1=0,sm2=0,sm3=0, s20=0,s21=0,s22=0,s23=0;
    #pragma unroll
    for (int ft = 0; ft < 8; ++ft){
      float bv = hb1[ft*16 + r15];
      float v0 = acc[ft][0]+bv, v1 = acc[ft][1]+bv, v2 = acc[ft][2]+bv, v3 = acc[ft][3]+bv;
      acc[ft][0]=v0; acc[ft][1]=v1; acc[ft][2]=v2; acc[ft][3]=v3;
      sm0+=v0; sm1+=v1; sm2+=v2; sm3+=v3;
      s20+=v0*v0; s21+=v1*v1; s22+=v2*v2; s23+=v3*v3;
    }
    sm0=qred16(sm0); sm1=qred16(sm1); sm2=qred16(sm2); sm3=qred16(sm3);
    s20=qred16(s20); s21=qred16(s21); s22=qred16(s22); s23=qred16(s23);
    float mean[4] = { sm0*(1.f/128.f), sm1*(1.f/128.f), sm2*(1.f/128.f), sm3*(1.f/128.f) };
    float rstd[4] = { rsqrtf(s20*(1.f/128.f)-mean[0]*mean[0]+1e-5f),
                      rsqrtf(s21*(1.f/128.f)-mean[1]*mean[1]+1e-5f),
                      rsqrtf(s22*(1.f/128.f)-mean[2]*mean[2]+1e-5f),
                      rsqrtf(s23*(1.f/128.f)-mean[3]*mean[3]+1e-5f) };
    float part0=0, part1=0, part2=0, part3=0;
    #pragma unroll
    for (int ft = 0; ft < 8; ++ft){
      float gv = hg[ft*16 + r15], bbv = hbb[ft*16 + r15], w2v = hw2[ft*16 + r15];
      part0 += gelu_f((acc[ft][0]-mean[0])*rstd[0]*gv + bbv) * w2v;
      part1 += gelu_f((acc[ft][1]-mean[1])*rstd[1]*gv + bbv) * w2v;
      part2 += gelu_f((acc[ft][2]-mean[2])*rstd[2]*gv + bbv) * w2v;
      part3 += gelu_f((acc[ft][3]-mean[3])*rstd[3]*gv + bbv) * w2v;
    }
    part0=qred16(part0); part1=qred16(part1); part2=qred16(part2); part3=qred16(part3);
    float parts[4] = { part0, part1, part2, part3 };
    #pragma unroll
    for (int j = 0; j < 4; ++j){
      if (r15 == j){
        int row = q * 4 + j;
        float ps = parts[j] + hb2[0];
        float spl = fmaxf(ps, 0.f) + log1pf(expf(-fabsf(ps)));
        float dn = den_in[row0 + row];
        pt_out[row0 + row] = 5.f - 1.5f*dn + 0.5f*spl;
      }
    }
  }
}

// ---------------- fused attention + upd: block = (b, 32 n's), 512 blocks = 2/CU ----------------
__global__ __launch_bounds__(256) void k_attn_upd(const float* __restrict__ spatial, const float* __restrict__ pt_in,
    const float* __restrict__ den_in, const float* __restrict__ objp, int ob_stride,
    const float* __restrict__ nsqp, int nq_stride,
    const float* __restrict__ lt, const float* __restrict__ bh, const float* __restrict__ hs,
    float* __restrict__ attn_out, int writeAttn,
    float* __restrict__ upd_raw, float* __restrict__ Ssum){
  __shared__ float abuf[24][33];
  int blk = blockIdx.x;
  int b = blk >> 6, chunk = blk & 63;
  int n0 = chunk * 32;
  int t = threadIdx.x;
  int sub = t & 7, rl = t >> 3;      // rl in [0,32), 8 threads/row, 16 floats each
  int id = b * cN + n0 + rl;

  { // ---- phase 1: attention ----
    float4 sv[4];
    const float4* sp4 = (const float4*)(spatial + (size_t)id * cH + sub * 16);
    #pragma unroll
    for (int i = 0; i < 4; ++i) sv[i] = sp4[i];
    float spn2 = 0.f;
    #pragma unroll
    for (int i = 0; i < 4; ++i) spn2 += sv[i].x*sv[i].x + sv[i].y*sv[i].y + sv[i].z*sv[i].z + sv[i].w*sv[i].w;

    const float* ob = objp + (size_t)b * ob_stride;
    float acc[8];
    #pragma unroll
    for (int o = 0; o < 8; ++o){
      const float4* orow = (const float4*)(ob + (size_t)o * cH + sub * 16);
      float a0=0,a1=0,a2=0,a3=0;
      #pragma unroll
      for (int i = 0; i < 4; ++i){ float4 w4 = orow[i];
        a0 += w4.x*sv[i].x; a1 += w4.y*sv[i].y; a2 += w4.z*sv[i].z; a3 += w4.w*sv[i].w; }
      acc[o] = (a0+a1)+(a2+a3);
    }
    spn2 += __shfl_xor(spn2, 1); spn2 += __shfl_xor(spn2, 2); spn2 += __shfl_xor(spn2, 4);
    #pragma unroll
    for (int o = 0; o < 8; ++o){
      acc[o] += __shfl_xor(acc[o], 1); acc[o] += __shfl_xor(acc[o], 2); acc[o] += __shfl_xor(acc[o], 4);
    }

    if (sub == 0){
      const float* nq = nsqp + (size_t)b * nq_stride;
      float nsqv_[8];
      #pragma unroll
      for (int o = 0; o < 8; ++o) nsqv_[o] = nq[o];
      float pt = pt_in[id], den = den_in[id];
      float hsv = hs[0];
      float lts[3] = { lt[0], lt[1], lt[2] };
      float bhs[3] = { bh[0], bh[1], bh[2] };

      float logits[24];
      #pragma unroll
      for (int k = 0; k < 24; ++k){
        const int o = k / 3, l = k % 3;
        float dtv = pt - lts[l];
        float dr2 = fmaxf(spn2 + nsqv_[o] - 2.f * acc[o], 0.f);
        float ls  = dtv*dtv - dr2;
        float adL = sqrtf(fabsf(ls) + 1e-6f);
        float r   = sqrtf(dr2);
        float adt = fabsf(dtv);
        float hz  = fminf(fmaxf(bhs[l] + hsv * (den - 0.5f), 0.1f), 1.0f);
        float cone = hz - r / (adt + 1e-6f) - 10.f * fmaxf(-dtv, 0.f) - 5.f * fmaxf(r - adt, 0.f);
        logits[k] = (-adL + 0.5f * tanhf(cone)) * 10.f;
      }
      float mx = -3e38f;
      #pragma unroll
      for (int k = 0; k < 24; ++k) mx = fmaxf(mx, logits[k]);
      float es[24]; float ssum = 0.f;
      #pragma unroll
      for (int k = 0; k < 24; ++k){ es[k] = expf(logits[k] - mx); ssum += es[k]; }
      float inv = 1.f / ssum;
      #pragma unroll
      for (int k = 0; k < 24; ++k) abuf[k][rl] = es[k] * inv;
    }
  }
  __syncthreads();

  if (writeAttn){  // coalesced copy LDS -> global (last iteration only): 24*32 = 768 = 3*256
    float* ao = attn_out + (size_t)b * cK * cN + n0;
    #pragma unroll
    for (int i = 0; i < 3; ++i){
      int idx = t + i * 256;
      ao[(size_t)(idx >> 5) * cN + (idx & 31)] = abuf[idx >> 5][idx & 31];
    }
  }

  // ---- phase 2: upd accumulate ----
  int h = t & 127, g = t >> 7;
  float acc2[12];
  #pragma unroll
  for (int kk = 0; kk < 12; ++kk) acc2[kk] = 0.f;
  const float* sp = spatial + ((size_t)b * cN + n0) * cH + h;
  for (int ni = 0; ni < 32; ++ni){
    float spv = sp[(size_t)ni * cH];
    #pragma unroll
    for (int kk = 0; kk < 12; ++kk) acc2[kk] += abuf[g*12+kk][ni] * spv;
  }
  #pragma unroll
  for (int kk = 0; kk < 12; ++kk)
    atomicAdd(&upd_raw[((size_t)b * cK + g*12+kk) * cH + h], acc2[kk]);
  if (t < 24){
    float s = 0.f;
    #pragma unroll
    for (int j = 0; j < 32; ++j) s += abuf[t][j];
    atomicAdd(&Ssum[b * cK + t], s);
  }
}

// ---------------- GRU + LN + MLP residual ----------------
__global__ __launch_bounds__(128) void k_gru(const float* __restrict__ upd_raw, const float* __restrict__ Ssum,
    const float* __restrict__ ghs, const float* __restrict__ objsp,
    const float* __restrict__ w_ih, const float* __restrict__ b_ih,
    const float* __restrict__ mw1, const float* __restrict__ mb1,
    const float* __restrict__ mw2, const float* __restrict__ mb2,
    const float* __restrict__ ng_, const float* __restrict__ nb_,
    const float* __restrict__ lt,
    float* __restrict__ newobj, float* __restrict__ nsq,
    float* __restrict__ slots_out, int writeSlots){
  __shared__ float ubuf[cH], lbuf[cH], gbuf[cH], red[8];
  int bo = blockIdx.x; int b = bo >> 3, o = bo & 7;
  int t = threadIdx.x;
  int lane = t & 63, wid = t >> 6;

  float u = 0.f;
  #pragma unroll
  for (int l = 0; l < 3; ++l){
    int k = o * 3 + l;
    float s = Ssum[b * cK + k] + 1e-8f;
    u += upd_raw[((size_t)b * cK + k) * cH + t] / s;
  }
  ubuf[t] = u;
  __syncthreads();

  float gi[3];
  #pragma unroll
  for (int j3 = 0; j3 < 3; ++j3){
    const float* wr = w_ih + ((size_t)j3 * cH + t) * cH;
    float a0=0,a1=0,a2=0,a3=0;
    #pragma unroll
    for (int d = 0; d < cH; d += 4){
      a0 += wr[d]*ubuf[d]; a1 += wr[d+1]*ubuf[d+1]; a2 += wr[d+2]*ubuf[d+2]; a3 += wr[d+3]*ubuf[d+3];
    }
    gi[j3] = (a0+a1)+(a2+a3) + b_ih[j3 * cH + t];
  }
  const float* gh = ghs + (size_t)o * 3 * cH;
  float ghr = gh[t], ghz = gh[cH + t], ghn = gh[2 * cH + t];
  float oldv = objsp[(size_t)o * cH + t];
  float rg = 1.f / (1.f + expf(-(gi[0] + ghr)));
  float zg = 1.f / (1.f + expf(-(gi[1] + ghz)));
  float ngv = tanhf(gi[2] + rg * ghn);
  float nv = (1.f - zg) * ngv + zg * oldv;

  float s1 = nv, s2 = nv * nv;
  #pragma unroll
  for (int m = 1; m < 64; m <<= 1){ s1 += __shfl_xor(s1, m); s2 += __shfl_xor(s2, m); }
  if (lane == 0){ red[wid] = s1; red[4 + wid] = s2; }
  __syncthreads();
  float mean = (red[0] + red[1]) * (1.f/128.f);
  float var  = (red[4] + red[5]) * (1.f/128.f) - mean * mean;
  float ln = (nv - mean) * rsqrtf(var + 1e-5f) * ng_[t] + nb_[t];
  lbuf[t] = ln;
  __syncthreads();

  const float* w1r = mw1 + (size_t)t * cH;
  {
    float a0=0,a1=0,a2=0,a3=0;
    #pragma unroll
    for (int d = 0; d < cH; d += 4){
      a0 += w1r[d]*lbuf[d]; a1 += w1r[d+1]*lbuf[d+1]; a2 += w1r[d+2]*lbuf[d+2]; a3 += w1r[d+3]*lbuf[d+3];
    }
    gbuf[t] = gelu_f((a0+a1)+(a2+a3) + mb1[t]);
  }
  __syncthreads();
  const float* w2r = mw2 + (size_t)t * cH;
  float m2v;
  {
    float a0=0,a1=0,a2=0,a3=0;
    #pragma unroll
    for (int d = 0; d < cH; d += 4){
      a0 += w2r[d]*gbuf[d]; a1 += w2r[d+1]*gbuf[d+1]; a2 += w2r[d+2]*gbuf[d+2]; a3 += w2r[d+3]*gbuf[d+3];
    }
    m2v = (a0+a1)+(a2+a3) + mb2[t];
  }
  float outv = nv + 0.2f * m2v;
  newobj[((size_t)b * cO + o) * cH + t] = outv;

  float qv = outv * outv;
  #pragma unroll
  for (int m = 1; m < 64; m <<= 1) qv += __shfl_xor(qv, m);
  __syncthreads();
  if (lane == 0) red[wid] = qv;
  __syncthreads();
  if (t == 0) nsq[b * cO + o] = red[0] + red[1];

  if (writeSlots){
    #pragma unroll
    for (int l = 0; l < 3; ++l){
      size_t base = ((size_t)b * cK + o * 3 + l) * 129;
      slots_out[base + 1 + t] = outv;
      if (t == 0) slots_out[base] = lt[l];
    }
  }
}

extern "C" void kernel_launch(void* const* d_in, const int* in_sizes, int n_in,
                              void* d_out, int out_size, void* d_ws, size_t ws_size,
                              hipStream_t stream){
  const float* x       = (const float*)d_in[0];
  const float* enc_w1  = (const float*)d_in[1];
  const float* enc_b1  = (const float*)d_in[2];
  const float* enc_g1  = (const float*)d_in[3];
  const float* enc_bb1 = (const float*)d_in[4];
  const float* enc_w2  = (const float*)d_in[5];
  const float* enc_b2  = (const float*)d_in[6];
  const float* enc_g2  = (const float*)d_in[7];
  const float* enc_bb2 = (const float*)d_in[8];
  const float* sp_w1   = (const float*)d_in[9];
  const float* sp_b1   = (const float*)d_in[10];
  const float* sp_g    = (const float*)d_in[11];
  const float* sp_bb   = (const float*)d_in[12];
  const float* sp_w2   = (const float*)d_in[13];
  const float* sp_b2   = (const float*)d_in[14];
  const float* objsp   = (const float*)d_in[15];
  const float* hscale  = (const float*)d_in[16];
  const float* ltimes  = (const float*)d_in[17];
  const float* bhor    = (const float*)d_in[18];
  const float* gw_ih   = (const float*)d_in[19];
  const float* gw_hh   = (const float*)d_in[20];
  const float* gb_ih   = (const float*)d_in[21];
  const float* gb_hh   = (const float*)d_in[22];
  const float* mw1     = (const float*)d_in[23];
  const float* mb1     = (const float*)d_in[24];
  const float* mw2     = (const float*)d_in[25];
  const float* mb2     = (const float*)d_in[26];
  const float* normg   = (const float*)d_in[27];
  const float* normb   = (const float*)d_in[28];
  (void)in_sizes; (void)n_in; (void)out_size; (void)ws_size;

  float* out = (float*)d_out;
  float* ws  = (float*)d_ws;

  float* spatial = ws + WS_SPATIAL;
  float* sq      = ws + WS_SQ;
  float* ghs     = ws + WS_GHS;
  float* nsq0    = ws + WS_NSQ0;
  float* newobj  = ws + WS_NEWOBJ;
  float* nsqv    = ws + WS_NSQ;
  short* wf      = (short*)(ws + WS_WFRAG);
  float* updr3   = ws + WS_UPD3;
  float* Ss3     = ws + WS_S3;
  short* xbf     = (short*)(ws + WS_XBF);

  hipMemsetAsync((void*)updr3, 0, (size_t)(3 * cB * cK * cH + 3 * cB * cK) * sizeof(float), stream);

  k_cvt_sq<<<dim3(ROWS / 32), dim3(256), 0, stream>>>(x, xbf, sq);
  k_prep<<<dim3(189), dim3(256), 0, stream>>>(objsp, gw_hh, gb_hh, enc_w1, enc_w2, sp_w1,
                                              ghs, nsq0, wf);
  k_pairwise<<<dim3(cB * (cN / 16)), dim3(256), 0, stream>>>(xbf, sq, out + OUT_DEN);
  k_enc_head<<<dim3(ROWS / 32), dim3(128), 0, stream>>>(x, out + OUT_DEN, wf,
      enc_b1, enc_g1, enc_bb1, enc_b2, enc_g2, enc_bb2,
      sp_b1, sp_g, sp_bb, sp_w2, sp_b2,
      spatial, out + OUT_PT);

  for (int it = 0; it < 3; ++it){
    float* updr = updr3 + (size_t)it * cB * cK * cH;
    float* Ss   = Ss3 + (size_t)it * cB * cK;
    const float* objp = (it == 0) ? objsp : newobj;
    int obst = (it == 0) ? 0 : cO * cH;
    const float* nqp = (it == 0) ? nsq0 : nsqv;
    int nqst = (it == 0) ? 0 : cO;
    k_attn_upd<<<dim3(cB * 64), dim3(256), 0, stream>>>(spatial, out + OUT_PT, out + OUT_DEN,
                                                        objp, obst, nqp, nqst,
                                                        ltimes, bhor, hscale,
                                                        out + OUT_ATTN, (it == 2) ? 1 : 0,
                                                        updr, Ss);
    k_gru<<<dim3(cB * cO), dim3(128), 0, stream>>>(updr, Ss, ghs, objsp, gw_ih, gb_ih,
                                                   mw1, mb1, mw2, mb2, normg, normb, ltimes,
                                                   newobj, nsqv, out + OUT_SLOTS, (it == 2) ? 1 : 0);
  }
}

// Round 11
// 299.289 us; speedup vs baseline: 1.1376x; 1.0134x over previous
//
#include <hip/hip_runtime.h>
#include <math.h>

// ---- problem dims ----
constexpr int cB = 8, cN = 2048, cI = 64, cH = 128, cO = 8, cK = 24;
constexpr int ROWS = cB * cN; // 16384

// ---- ws layout (floats) ----
constexpr size_t WS_SPATIAL = 0;                                  // 16384*128
constexpr size_t WS_SQ      = WS_SPATIAL + (size_t)ROWS * cH;     // 16384
constexpr size_t WS_GHS     = WS_SQ + ROWS;                       // 8*384
constexpr size_t WS_NSQ0    = WS_GHS + (size_t)cO * 3 * cH;       // 8
constexpr size_t WS_NEWOBJ  = WS_NSQ0 + cO;                       // 8*8*128
constexpr size_t WS_NSQ     = WS_NEWOBJ + (size_t)cB * cO * cH;   // 64
constexpr size_t WS_WFRAG   = WS_NSQ + (size_t)cB * cO;           // 90112 shorts = 45056 floats
constexpr size_t WS_UPD3    = WS_WFRAG + 45056;                   // 3*8*24*128
constexpr size_t WS_S3      = WS_UPD3 + (size_t)3 * cB * cK * cH; // 3*8*24
constexpr size_t WS_XBF     = WS_S3 + (size_t)3 * cB * cK;        // 16384*64 bf16

// weight-fragment sub-offsets (in shorts, within WFRAG)
constexpr size_t WF_W1H = 0;        // 8*2*64*8  = 8192
constexpr size_t WF_W1L = 8192;
constexpr size_t WF_W2H = 16384;    // 8*4*64*8  = 16384
constexpr size_t WF_W2L = 32768;
constexpr size_t WF_WHH = 49152;    // 8*5*64*8  = 20480
constexpr size_t WF_WHL = 69632;    // total 90112

// zero region: updr3 + Ss3, contiguous
constexpr int ZERO_FLOATS = 3 * cB * cK * cH + 3 * cB * cK;       // 74304
constexpr int ZERO_F4     = ZERO_FLOATS / 4;                      // 18576

// ---- d_out layout (floats), return order: slots, attn, pred_time, density ----
constexpr size_t OUT_SLOTS = 0;
constexpr size_t OUT_ATTN  = (size_t)cB * cK * 129;
constexpr size_t OUT_PT    = OUT_ATTN + (size_t)cB * cK * cN;
constexpr size_t OUT_DEN   = OUT_PT + (size_t)cB * cN;

typedef __attribute__((ext_vector_type(8))) short bf16x8;
typedef __attribute__((ext_vector_type(4))) float f32x4;

__device__ __forceinline__ float gelu_f(float v){
  return 0.5f * v * (1.f + erff(v * 0.70710678118654752440f));
}
__device__ __forceinline__ short f2bf(float f){
  unsigned u = __float_as_uint(f);
  u += 0x7fffu + ((u >> 16) & 1u);   // RNE
  return (short)(u >> 16);
}
__device__ __forceinline__ float bf2f(short h){
  return __uint_as_float(((unsigned)(unsigned short)h) << 16);
}
__device__ __forceinline__ bf16x8 pack8(float4 a, float4 b){
  bf16x8 r;
  r[0]=f2bf(a.x); r[1]=f2bf(a.y); r[2]=f2bf(a.z); r[3]=f2bf(a.w);
  r[4]=f2bf(b.x); r[5]=f2bf(b.y); r[6]=f2bf(b.z); r[7]=f2bf(b.w);
  return r;
}
__device__ __forceinline__ float qred16(float a){  // sum over lane&15 group
  a += __shfl_xor(a, 1); a += __shfl_xor(a, 2); a += __shfl_xor(a, 4); a += __shfl_xor(a, 8);
  return a;
}
// branchless sorted-insert of x into ascending 6-vector (keep 6 smallest):
// t0'=min(t0,x); tk'=med3(t(k-1),tk,x)  [1 v_min + 5 v_med3]
#define INS6(T0,T1,T2,T3,T4,T5,X) { \
  float _o0=T0,_o1=T1,_o2=T2,_o3=T3,_o4=T4,_o5=T5; \
  T0 = fminf(_o0, X); \
  T1 = __builtin_amdgcn_fmed3f(_o0,_o1,X); \
  T2 = __builtin_amdgcn_fmed3f(_o1,_o2,X); \
  T3 = __builtin_amdgcn_fmed3f(_o2,_o3,X); \
  T4 = __builtin_amdgcn_fmed3f(_o3,_o4,X); \
  T5 = __builtin_amdgcn_fmed3f(_o4,_o5,X); \
}
// f32 -> (hi,lo) bf16 split fragment from LDS (8 contiguous floats at off)
__device__ __forceinline__ void load_split_frag(const float* buf, int off, bf16x8& hi, bf16x8& lo){
  float4 u0 = *(const float4*)&buf[off];
  float4 u1 = *(const float4*)&buf[off + 4];
  float v[8] = {u0.x,u0.y,u0.z,u0.w,u1.x,u1.y,u1.z,u1.w};
  #pragma unroll
  for (int i = 0; i < 8; ++i){
    short h = f2bf(v[i]);
    hi[i] = h;
    lo[i] = f2bf(v[i] - bf2f(h));
  }
}
// swizzled LDS float-index: row*stride + (col ^ ((row&3)<<3))
__device__ __forceinline__ int lidx(int row, int col, int stride){
  return row * stride + (col ^ ((row & 3) << 3));
}

// ---------------- fused setup: [0,512) x->bf16 + ||x||^2 ; [512,701) prep ; [701,774) zero updr ----------------
__global__ __launch_bounds__(256) void k_setup(const float* __restrict__ x, short* __restrict__ xbf,
                                               float* __restrict__ sq,
                                               const float* __restrict__ objsp, const float* __restrict__ w_hh,
                                               const float* __restrict__ b_hh,
                                               const float* __restrict__ ew1, const float* __restrict__ ew2,
                                               const float* __restrict__ spw1,
                                               float* __restrict__ ghs, float* __restrict__ nsq0,
                                               short* __restrict__ wf,
                                               float* __restrict__ zero_base){
  int bid = blockIdx.x;
  int t = threadIdx.x;
  if (bid < 512){
    // ---- cvt + sq ----
    size_t base = (size_t)bid * 2048;
    int r = t >> 3, e0 = (t & 7) * 8;
    const float4* xp = (const float4*)(x + base + (size_t)r * cI + e0);
    float4 v0 = xp[0], v1 = xp[1];
    *(bf16x8*)(xbf + base + (size_t)r * cI + e0) = pack8(v0, v1);
    float s = v0.x*v0.x + v0.y*v0.y + v0.z*v0.z + v0.w*v0.w
            + v1.x*v1.x + v1.y*v1.y + v1.z*v1.z + v1.w*v1.w;
    s += __shfl_xor(s, 1); s += __shfl_xor(s, 2); s += __shfl_xor(s, 4);
    if ((t & 7) == 0) sq[bid * 32 + r] = s;
  } else if (bid < 701){
    // ---- prep: ghs, nsq0, split-bf16 weight fragments ----
    int id = (bid - 512) * 256 + t;
    if (id < cO * 3 * cH){
      int o = id / (3 * cH), j = id % (3 * cH);
      const float* wr = w_hh + (size_t)j * cH;
      const float* ob = objsp + (size_t)o * cH;
      float a0=0,a1=0,a2=0,a3=0;
      #pragma unroll
      for (int h = 0; h < cH; h += 4){
        a0 += wr[h]*ob[h]; a1 += wr[h+1]*ob[h+1]; a2 += wr[h+2]*ob[h+2]; a3 += wr[h+3]*ob[h+3];
      }
      ghs[id] = (a0+a1)+(a2+a3) + b_hh[j];
    } else if (id < cO * 3 * cH + cO){
      int o = id - cO * 3 * cH;
      const float* ob = objsp + (size_t)o * cH;
      float s = 0.f;
      for (int h = 0; h < cH; ++h) s += ob[h]*ob[h];
      nsq0[o] = s;
    } else {
      int idx = id - (cO * 3 * cH + cO);
      if (idx >= 45056) return;
      float w; size_t hoff, loff;
      int e, nc;
      if (idx < 8192){                 // W1: nc=2, K=64
        e = idx; nc = 2;
        int i = e & 7, l = (e >> 3) & 63, r = e >> 9;
        int c = r % nc, ft = r / nc;
        int f = ft * 16 + (l & 15), k = c * 32 + (l >> 4) * 8 + i;
        w = ew1[f * cI + k];
        hoff = WF_W1H + e; loff = WF_W1L + e;
      } else if (idx < 24576){         // W2: nc=4, K=128
        e = idx - 8192; nc = 4;
        int i = e & 7, l = (e >> 3) & 63, r = e >> 9;
        int c = r % nc, ft = r / nc;
        int f = ft * 16 + (l & 15), k = c * 32 + (l >> 4) * 8 + i;
        w = ew2[f * cH + k];
        hoff = WF_W2H + e; loff = WF_W2L + e;
      } else {                         // HW: nc=5, K=160 (k<129 real, else 0)
        e = idx - 24576; nc = 5;
        int i = e & 7, l = (e >> 3) & 63, r = e >> 9;
        int c = r % nc, ft = r / nc;
        int f = ft * 16 + (l & 15), k = c * 32 + (l >> 4) * 8 + i;
        w = (k < 129) ? spw1[f * 129 + k] : 0.f;
        hoff = WF_WHH + e; loff = WF_WHL + e;
      }
      short h = f2bf(w);
      wf[hoff] = h;
      wf[loff] = f2bf(w - bf2f(h));
    }
  } else {
    // ---- zero updr3 + Ss3 ----
    int idx = (bid - 701) * 256 + t;
    if (idx < ZERO_F4){
      float4 z = {0.f, 0.f, 0.f, 0.f};
      *(float4*)(zero_base + (size_t)idx * 4) = z;
    }
  }
}

// ---------------- pairwise distances (bf16) + fused per-row top-6 -> density ----------------
__global__ __launch_bounds__(256) void k_pairwise(const short* __restrict__ xbf, const float* __restrict__ sq,
                                                  float* __restrict__ den_out){
  __shared__ float cand[4][16][101];
  int b  = blockIdx.x >> 7;
  int rt = blockIdx.x & 127;
  int r0 = rt * 16;
  int lane = threadIdx.x & 63, w = threadIdx.x >> 6;
  const short* xb = xbf + (size_t)b * cN * cI;

  int arow = r0 + (lane & 15);
  int koff = (lane >> 4) * 8;
  const bf16x8* ap = (const bf16x8*)(xb + (size_t)arow * cI + koff);
  bf16x8 a0 = ap[0];
  bf16x8 a1 = ap[4];

  float sqr[4];
  int rg0 = r0 + ((lane >> 4) << 2);
  #pragma unroll
  for (int j = 0; j < 4; ++j) sqr[j] = sq[b * cN + rg0 + j];

  float t6[4][6];
  #pragma unroll
  for (int j = 0; j < 4; ++j){
    #pragma unroll
    for (int q = 0; q < 6; ++q) t6[j][q] = 3e38f;
  }

  int cbase = w * 512;
  #pragma unroll 2
  for (int ct = 0; ct < 32; ++ct){
    int col0 = cbase + ct * 16;
    int brow = col0 + (lane & 15);
    const bf16x8* bp = (const bf16x8*)(xb + (size_t)brow * cI + koff);
    bf16x8 b0 = bp[0];
    bf16x8 b1 = bp[4];
    f32x4 acc = {0.f, 0.f, 0.f, 0.f};
    acc = __builtin_amdgcn_mfma_f32_16x16x32_bf16(a0, b0, acc, 0, 0, 0);
    acc = __builtin_amdgcn_mfma_f32_16x16x32_bf16(a1, b1, acc, 0, 0, 0);
    float sqc = sq[b * cN + col0 + (lane & 15)];
    #pragma unroll
    for (int j = 0; j < 4; ++j){
      float d2 = sqr[j] + sqc - 2.f * acc[j];
      d2 = fmaxf(d2, 0.f);
      if (d2 < t6[j][5]){                       // exec-mask skip: rare after warm-up
        INS6(t6[j][0], t6[j][1], t6[j][2], t6[j][3], t6[j][4], t6[j][5], d2);
      }
    }
  }
  int rloc = (lane >> 4) << 2;
  #pragma unroll
  for (int j = 0; j < 4; ++j){
    #pragma unroll
    for (int q = 0; q < 6; ++q) cand[w][rloc + j][(lane & 15) * 6 + q] = t6[j][q];
  }
  __syncthreads();
  int tt = threadIdx.x;
  if (tt < 64){
    int ww = tt >> 4, rr = tt & 15;
    const float* c = cand[ww][rr];
    float m0=3e38f,m1=3e38f,m2=3e38f,m3=3e38f,m4=3e38f,m5=3e38f;
    #pragma unroll
    for (int q = 0; q < 96; ++q){
      float v = c[q];
      if (v < m5){
        INS6(m0, m1, m2, m3, m4, m5, v);
      }
    }
    float* cw = cand[ww][rr];
    cw[0]=m0; cw[1]=m1; cw[2]=m2; cw[3]=m3; cw[4]=m4; cw[5]=m5;
  }
  __syncthreads();
  if (tt < 16){
    float m0=3e38f,m1=3e38f,m2=3e38f,m3=3e38f,m4=3e38f,m5=3e38f;
    #pragma unroll
    for (int ww = 0; ww < 4; ++ww){
      const float* c = cand[ww][tt];
      #pragma unroll
      for (int q = 0; q < 6; ++q){
        float v = c[q];
        INS6(m0, m1, m2, m3, m4, m5, v);
      }
    }
    float md = (sqrtf(m1)+sqrtf(m2)+sqrtf(m3)+sqrtf(m4)+sqrtf(m5)) * 0.2f;
    den_out[b * cN + r0 + tt] = tanhf(md);
  }
}

// ---------------- fused encoder + head via split-bf16 MFMA ----------------
// block = 128 thr = 2 waves; wave = 16 rows x 128 features. grid = ROWS/32 = 512.
__global__ __launch_bounds__(128) void k_enc_head(const float* __restrict__ x, const float* __restrict__ den_in,
    const short* __restrict__ wf,
    const float* __restrict__ b1, const float* __restrict__ g1, const float* __restrict__ bb1,
    const float* __restrict__ b2, const float* __restrict__ g2, const float* __restrict__ bb2,
    const float* __restrict__ hb1, const float* __restrict__ hg, const float* __restrict__ hbb,
    const float* __restrict__ hw2, const float* __restrict__ hb2,
    float* __restrict__ spatial, float* __restrict__ pt_out){
  __shared__ __align__(16) float xs_[2][16 * 68];
  __shared__ __align__(16) float hs_[2][16 * 164];
  const int t = threadIdx.x, lane = t & 63, wv = t >> 6;
  const int row0 = blockIdx.x * 32 + wv * 16;
  float* xbuf = xs_[wv];
  float* hbuf = hs_[wv];
  const int r15 = lane & 15, q = lane >> 4;
  const int qx = (q ^ (r15 & 3)) << 3;   // swizzled k-offset base for fragment reads

  // ---- stage 16 x-rows into swizzled LDS (coalesced) ----
  {
    const float4* xg = (const float4*)(x + (size_t)row0 * cI);
    #pragma unroll
    for (int k = 0; k < 4; ++k){
      int f4 = k * 64 + lane;               // 0..255
      int row = f4 >> 4, c4 = (f4 & 15) * 4;
      float4 v = xg[f4];
      *(float4*)&xbuf[lidx(row, c4, 68)] = v;
    }
  }
  __syncthreads();

  f32x4 acc[8];
  const short* w1h = wf + WF_W1H; const short* w1l = wf + WF_W1L;
  const short* w2h = wf + WF_W2H; const short* w2l = wf + WF_W2L;
  const short* whh = wf + WF_WHH; const short* whl = wf + WF_WHL;

  // ================= layer 1: K=64 (2 chunks) =================
  #pragma unroll
  for (int ft = 0; ft < 8; ++ft) acc[ft] = (f32x4){0.f,0.f,0.f,0.f};
  #pragma unroll
  for (int c = 0; c < 2; ++c){
    bf16x8 ah, al;
    load_split_frag(xbuf, r15 * 68 + c * 32 + qx, ah, al);
    #pragma unroll
    for (int ft = 0; ft < 8; ++ft){
      bf16x8 bh = *(const bf16x8*)&w1h[(size_t)(((ft*2 + c)*64) + lane) * 8];
      bf16x8 bl = *(const bf16x8*)&w1l[(size_t)(((ft*2 + c)*64) + lane) * 8];
      acc[ft] = __builtin_amdgcn_mfma_f32_16x16x32_bf16(al, bh, acc[ft], 0, 0, 0);
      acc[ft] = __builtin_amdgcn_mfma_f32_16x16x32_bf16(ah, bl, acc[ft], 0, 0, 0);
      acc[ft] = __builtin_amdgcn_mfma_f32_16x16x32_bf16(ah, bh, acc[ft], 0, 0, 0);
    }
  }
  { // LN + gelu -> hbuf
    float sm0=0,sm1=0,sm2=0,sm3=0, s20=0,s21=0,s22=0,s23=0;
    #pragma unroll
    for (int ft = 0; ft < 8; ++ft){
      float bv = b1[ft*16 + r15];
      float v0 = acc[ft][0]+bv, v1 = acc[ft][1]+bv, v2 = acc[ft][2]+bv, v3 = acc[ft][3]+bv;
      acc[ft][0]=v0; acc[ft][1]=v1; acc[ft][2]=v2; acc[ft][3]=v3;
      sm0+=v0; sm1+=v1; sm2+=v2; sm3+=v3;
      s20+=v0*v0; s21+=v1*v1; s22+=v2*v2; s23+=v3*v3;
    }
    sm0=qred16(sm0); sm1=qred16(sm1); sm2=qred16(sm2); sm3=qred16(sm3);
    s20=qred16(s20); s21=qred16(s21); s22=qred16(s22); s23=qred16(s23);
    float mean[4] = { sm0*(1.f/128.f), sm1*(1.f/128.f), sm2*(1.f/128.f), sm3*(1.f/128.f) };
    float rstd[4] = { rsqrtf(s20*(1.f/128.f)-mean[0]*mean[0]+1e-5f),
                      rsqrtf(s21*(1.f/128.f)-mean[1]*mean[1]+1e-5f),
                      rsqrtf(s22*(1.f/128.f)-mean[2]*mean[2]+1e-5f),
                      rsqrtf(s23*(1.f/128.f)-mean[3]*mean[3]+1e-5f) };
    #pragma unroll
    for (int ft = 0; ft < 8; ++ft){
      float gv = g1[ft*16 + r15], bbv = bb1[ft*16 + r15];
      #pragma unroll
      for (int j = 0; j < 4; ++j){
        float e = gelu_f((acc[ft][j]-mean[j])*rstd[j]*gv + bbv);
        hbuf[lidx(q*4 + j, ft*16 + r15, 164)] = e;
      }
    }
  }
  __syncthreads();

  // ================= layer 2: K=128 (4 chunks) =================
  #pragma unroll
  for (int ft = 0; ft < 8; ++ft) acc[ft] = (f32x4){0.f,0.f,0.f,0.f};
  #pragma unroll
  for (int c = 0; c < 4; ++c){
    bf16x8 ah, al;
    load_split_frag(hbuf, r15 * 164 + c * 32 + qx, ah, al);
    #pragma unroll
    for (int ft = 0; ft < 8; ++ft){
      bf16x8 bh = *(const bf16x8*)&w2h[(size_t)(((ft*4 + c)*64) + lane) * 8];
      bf16x8 bl = *(const bf16x8*)&w2l[(size_t)(((ft*4 + c)*64) + lane) * 8];
      acc[ft] = __builtin_amdgcn_mfma_f32_16x16x32_bf16(al, bh, acc[ft], 0, 0, 0);
      acc[ft] = __builtin_amdgcn_mfma_f32_16x16x32_bf16(ah, bl, acc[ft], 0, 0, 0);
      acc[ft] = __builtin_amdgcn_mfma_f32_16x16x32_bf16(ah, bh, acc[ft], 0, 0, 0);
    }
  }
  __syncthreads();   // all hbuf reads done before overwrite
  { // LN (no gelu) -> spatial values into hbuf cols 0..127 + den/zeros cols 128..159
    float sm0=0,sm1=0,sm2=0,sm3=0, s20=0,s21=0,s22=0,s23=0;
    #pragma unroll
    for (int ft = 0; ft < 8; ++ft){
      float bv = b2[ft*16 + r15];
      float v0 = acc[ft][0]+bv, v1 = acc[ft][1]+bv, v2 = acc[ft][2]+bv, v3 = acc[ft][3]+bv;
      acc[ft][0]=v0; acc[ft][1]=v1; acc[ft][2]=v2; acc[ft][3]=v3;
      sm0+=v0; sm1+=v1; sm2+=v2; sm3+=v3;
      s20+=v0*v0; s21+=v1*v1; s22+=v2*v2; s23+=v3*v3;
    }
    sm0=qred16(sm0); sm1=qred16(sm1); sm2=qred16(sm2); sm3=qred16(sm3);
    s20=qred16(s20); s21=qred16(s21); s22=qred16(s22); s23=qred16(s23);
    float mean[4] = { sm0*(1.f/128.f), sm1*(1.f/128.f), sm2*(1.f/128.f), sm3*(1.f/128.f) };
    float rstd[4] = { rsqrtf(s20*(1.f/128.f)-mean[0]*mean[0]+1e-5f),
                      rsqrtf(s21*(1.f/128.f)-mean[1]*mean[1]+1e-5f),
                      rsqrtf(s22*(1.f/128.f)-mean[2]*mean[2]+1e-5f),
                      rsqrtf(s23*(1.f/128.f)-mean[3]*mean[3]+1e-5f) };
    #pragma unroll
    for (int ft = 0; ft < 8; ++ft){
      float gv = g2[ft*16 + r15], bbv = bb2[ft*16 + r15];
      #pragma unroll
      for (int j = 0; j < 4; ++j){
        float s = (acc[ft][j]-mean[j])*rstd[j]*gv + bbv;
        hbuf[lidx(q*4 + j, ft*16 + r15, 164)] = s;
      }
    }
    // head-input tail: col 128 = den, 129..159 = 0
    #pragma unroll
    for (int i = 0; i < 8; ++i){
      int flat = lane * 8 + i;               // 0..511
      int row = flat >> 5, col = 128 + (flat & 31);
      float v = ((flat & 31) == 0) ? den_in[row0 + row] : 0.f;
      hbuf[lidx(row, col, 164)] = v;
    }
  }
  __syncthreads();

  // dump spatial (coalesced via LDS)
  {
    #pragma unroll
    for (int k = 0; k < 8; ++k){
      int f4 = k * 64 + lane;                // 0..511
      int row = f4 >> 5, c4 = (f4 & 31) * 4;
      float4 v = *(const float4*)&hbuf[lidx(row, c4, 164)];
      *(float4*)(spatial + (size_t)(row0 + row) * cH + c4) = v;
    }
  }

  // ================= head layer: K=160 (5 chunks) =================
  #pragma unroll
  for (int ft = 0; ft < 8; ++ft) acc[ft] = (f32x4){0.f,0.f,0.f,0.f};
  #pragma unroll
  for (int c = 0; c < 5; ++c){
    bf16x8 ah, al;
    load_split_frag(hbuf, r15 * 164 + c * 32 + qx, ah, al);
    #pragma unroll
    for (int ft = 0; ft < 8; ++ft){
      bf16x8 bh = *(const bf16x8*)&whh[(size_t)(((ft*5 + c)*64) + lane) * 8];
      bf16x8 bl = *(const bf16x8*)&whl[(size_t)(((ft*5 + c)*64) + lane) * 8];
      acc[ft] = __builtin_amdgcn_mfma_f32_16x16x32_bf16(al, bh, acc[ft], 0, 0, 0);
      acc[ft] = __builtin_amdgcn_mfma_f32_16x16x32_bf16(ah, bl, acc[ft], 0, 0, 0);
      acc[ft] = __builtin_amdgcn_mfma_f32_16x16x32_bf16(ah, bh, acc[ft], 0, 0, 0);
    }
  }
  { // LN + gelu + dot(hw2) + softplus -> pred_time
    float sm0=0,sm1=0,sm2=0,sm3=0, s20=0,s21=0,s22=0,s23=0;
    #pragma unroll
    for (int ft = 0; ft < 8; ++ft){
      float bv = hb1[ft*16 + r15];
      float v0 = acc[ft][0]+bv, v1 = acc[ft][1]+bv, v2 = acc[ft][2]+bv, v3 = acc[ft][3]+bv;
      acc[ft][0]=v0; acc[ft][1]=v1; acc[ft][2]=v2; acc[ft][3]=v3;
      sm0+=v0; sm1+=v1; sm2+=v2; sm3+=v3;
      s20+=v0*v0; s21+=v1*v1; s22+=v2*v2; s23+=v3*v3;
    }
    sm0=qred16(sm0); sm1=qred16(sm1); sm2=qred16(sm2); sm3=qred16(sm3);
    s20=qred16(s20); s21=qred16(s21); s22=qred16(s22); s23=qred16(s23);
    float mean[4] = { sm0*(1.f/128.f), sm1*(1.f/128.f), sm2*(1.f/128.f), sm3*(1.f/128.f) };
    float rstd[4] = { rsqrtf(s20*(1.f/128.f)-mean[0]*mean[0]+1e-5f),
                      rsqrtf(s21*(1.f/128.f)-mean[1]*mean[1]+1e-5f),
                      rsqrtf(s22*(1.f/128.f)-mean[2]*mean[2]+1e-5f),
                      rsqrtf(s23*(1.f/128.f)-mean[3]*mean[3]+1e-5f) };
    float part0=0, part1=0, part2=0, part3=0;
    #pragma unroll
    for (int ft = 0; ft < 8; ++ft){
      float gv = hg[ft*16 + r15], bbv = hbb[ft*16 + r15], w2v = hw2[ft*16 + r15];
      part0 += gelu_f((acc[ft][0]-mean[0])*rstd[0]*gv + bbv) * w2v;
      part1 += gelu_f((acc[ft][1]-mean[1])*rstd[1]*gv + bbv) * w2v;
      part2 += gelu_f((acc[ft][2]-mean[2])*rstd[2]*gv + bbv) * w2v;
      part3 += gelu_f((acc[ft][3]-mean[3])*rstd[3]*gv + bbv) * w2v;
    }
    part0=qred16(part0); part1=qred16(part1); part2=qred16(part2); part3=qred16(part3);
    float parts[4] = { part0, part1, part2, part3 };
    #pragma unroll
    for (int j = 0; j < 4; ++j){
      if (r15 == j){
        int row = q * 4 + j;
        float ps = parts[j] + hb2[0];
        float spl = fmaxf(ps, 0.f) + log1pf(expf(-fabsf(ps)));
        float dn = den_in[row0 + row];
        pt_out[row0 + row] = 5.f - 1.5f*dn + 0.5f*spl;
      }
    }
  }
}

// ---------------- fused attention + upd: block = (b, 32 n's), 512 blocks = 2/CU ----------------
__global__ __launch_bounds__(256) void k_attn_upd(const float* __restrict__ spatial, const float* __restrict__ pt_in,
    const float* __restrict__ den_in, const float* __restrict__ objp, int ob_stride,
    const float* __restrict__ nsqp, int nq_stride,
    const float* __restrict__ lt, const float* __restrict__ bh, const float* __restrict__ hs,
    float* __restrict__ attn_out, int writeAttn,
    float* __restrict__ upd_raw, float* __restrict__ Ssum){
  __shared__ float abuf[24][33];
  int blk = blockIdx.x;
  int b = blk >> 6, chunk = blk & 63;
  int n0 = chunk * 32;
  int t = threadIdx.x;
  int sub = t & 7, rl = t >> 3;      // rl in [0,32), 8 threads/row, 16 floats each
  int id = b * cN + n0 + rl;

  { // ---- phase 1: attention ----
    float4 sv[4];
    const float4* sp4 = (const float4*)(spatial + (size_t)id * cH + sub * 16);
    #pragma unroll
    for (int i = 0; i < 4; ++i) sv[i] = sp4[i];
    float spn2 = 0.f;
    #pragma unroll
    for (int i = 0; i < 4; ++i) spn2 += sv[i].x*sv[i].x + sv[i].y*sv[i].y + sv[i].z*sv[i].z + sv[i].w*sv[i].w;

    const float* ob = objp + (size_t)b * ob_stride;
    float acc[8];
    #pragma unroll
    for (int o = 0; o < 8; ++o){
      const float4* orow = (const float4*)(ob + (size_t)o * cH + sub * 16);
      float a0=0,a1=0,a2=0,a3=0;
      #pragma unroll
      for (int i = 0; i < 4; ++i){ float4 w4 = orow[i];
        a0 += w4.x*sv[i].x; a1 += w4.y*sv[i].y; a2 += w4.z*sv[i].z; a3 += w4.w*sv[i].w; }
      acc[o] = (a0+a1)+(a2+a3);
    }
    spn2 += __shfl_xor(spn2, 1); spn2 += __shfl_xor(spn2, 2); spn2 += __shfl_xor(spn2, 4);
    #pragma unroll
    for (int o = 0; o < 8; ++o){
      acc[o] += __shfl_xor(acc[o], 1); acc[o] += __shfl_xor(acc[o], 2); acc[o] += __shfl_xor(acc[o], 4);
    }

    if (sub == 0){
      const float* nq = nsqp + (size_t)b * nq_stride;
      float nsqv_[8];
      #pragma unroll
      for (int o = 0; o < 8; ++o) nsqv_[o] = nq[o];
      float pt = pt_in[id], den = den_in[id];
      float hsv = hs[0];
      float lts[3] = { lt[0], lt[1], lt[2] };
      float bhs[3] = { bh[0], bh[1], bh[2] };

      float logits[24];
      #pragma unroll
      for (int k = 0; k < 24; ++k){
        const int o = k / 3, l = k % 3;
        float dtv = pt - lts[l];
        float dr2 = fmaxf(spn2 + nsqv_[o] - 2.f * acc[o], 0.f);
        float ls  = dtv*dtv - dr2;
        float adL = sqrtf(fabsf(ls) + 1e-6f);
        float r   = sqrtf(dr2);
        float adt = fabsf(dtv);
        float hz  = fminf(fmaxf(bhs[l] + hsv * (den - 0.5f), 0.1f), 1.0f);
        float cone = hz - r / (adt + 1e-6f) - 10.f * fmaxf(-dtv, 0.f) - 5.f * fmaxf(r - adt, 0.f);
        logits[k] = (-adL + 0.5f * tanhf(cone)) * 10.f;
      }
      float mx = -3e38f;
      #pragma unroll
      for (int k = 0; k < 24; ++k) mx = fmaxf(mx, logits[k]);
      float es[24]; float ssum = 0.f;
      #pragma unroll
      for (int k = 0; k < 24; ++k){ es[k] = expf(logits[k] - mx); ssum += es[k]; }
      float inv = 1.f / ssum;
      #pragma unroll
      for (int k = 0; k < 24; ++k) abuf[k][rl] = es[k] * inv;
    }
  }
  __syncthreads();

  if (writeAttn){  // coalesced copy LDS -> global (last iteration only): 24*32 = 768 = 3*256
    float* ao = attn_out + (size_t)b * cK * cN + n0;
    #pragma unroll
    for (int i = 0; i < 3; ++i){
      int idx = t + i * 256;
      ao[(size_t)(idx >> 5) * cN + (idx & 31)] = abuf[idx >> 5][idx & 31];
    }
  }

  // ---- phase 2: upd accumulate ----
  int h = t & 127, g = t >> 7;
  float acc2[12];
  #pragma unroll
  for (int kk = 0; kk < 12; ++kk) acc2[kk] = 0.f;
  const float* sp = spatial + ((size_t)b * cN + n0) * cH + h;
  for (int ni = 0; ni < 32; ++ni){
    float spv = sp[(size_t)ni * cH];
    #pragma unroll
    for (int kk = 0; kk < 12; ++kk) acc2[kk] += abuf[g*12+kk][ni] * spv;
  }
  #pragma unroll
  for (int kk = 0; kk < 12; ++kk)
    atomicAdd(&upd_raw[((size_t)b * cK + g*12+kk) * cH + h], acc2[kk]);
  if (t < 24){
    float s = 0.f;
    #pragma unroll
    for (int j = 0; j < 32; ++j) s += abuf[t][j];
    atomicAdd(&Ssum[b * cK + t], s);
  }
}

// ---------------- GRU + LN + MLP residual ----------------
__global__ __launch_bounds__(128) void k_gru(const float* __restrict__ upd_raw, const float* __restrict__ Ssum,
    const float* __restrict__ ghs, const float* __restrict__ objsp,
    const float* __restrict__ w_ih, const float* __restrict__ b_ih,
    const float* __restrict__ mw1, const float* __restrict__ mb1,
    const float* __restrict__ mw2, const float* __restrict__ mb2,
    const float* __restrict__ ng_, const float* __restrict__ nb_,
    const float* __restrict__ lt,
    float* __restrict__ newobj, float* __restrict__ nsq,
    float* __restrict__ slots_out, int writeSlots){
  __shared__ float ubuf[cH], lbuf[cH], gbuf[cH], red[8];
  int bo = blockIdx.x; int b = bo >> 3, o = bo & 7;
  int t = threadIdx.x;
  int lane = t & 63, wid = t >> 6;

  float u = 0.f;
  #pragma unroll
  for (int l = 0; l < 3; ++l){
    int k = o * 3 + l;
    float s = Ssum[b * cK + k] + 1e-8f;
    u += upd_raw[((size_t)b * cK + k) * cH + t] / s;
  }
  ubuf[t] = u;
  __syncthreads();

  float gi[3];
  #pragma unroll
  for (int j3 = 0; j3 < 3; ++j3){
    const float* wr = w_ih + ((size_t)j3 * cH + t) * cH;
    float a0=0,a1=0,a2=0,a3=0;
    #pragma unroll
    for (int d = 0; d < cH; d += 4){
      a0 += wr[d]*ubuf[d]; a1 += wr[d+1]*ubuf[d+1]; a2 += wr[d+2]*ubuf[d+2]; a3 += wr[d+3]*ubuf[d+3];
    }
    gi[j3] = (a0+a1)+(a2+a3) + b_ih[j3 * cH + t];
  }
  const float* gh = ghs + (size_t)o * 3 * cH;
  float ghr = gh[t], ghz = gh[cH + t], ghn = gh[2 * cH + t];
  float oldv = objsp[(size_t)o * cH + t];
  float rg = 1.f / (1.f + expf(-(gi[0] + ghr)));
  float zg = 1.f / (1.f + expf(-(gi[1] + ghz)));
  float ngv = tanhf(gi[2] + rg * ghn);
  float nv = (1.f - zg) * ngv + zg * oldv;

  float s1 = nv, s2 = nv * nv;
  #pragma unroll
  for (int m = 1; m < 64; m <<= 1){ s1 += __shfl_xor(s1, m); s2 += __shfl_xor(s2, m); }
  if (lane == 0){ red[wid] = s1; red[4 + wid] = s2; }
  __syncthreads();
  float mean = (red[0] + red[1]) * (1.f/128.f);
  float var  = (red[4] + red[5]) * (1.f/128.f) - mean * mean;
  float ln = (nv - mean) * rsqrtf(var + 1e-5f) * ng_[t] + nb_[t];
  lbuf[t] = ln;
  __syncthreads();

  const float* w1r = mw1 + (size_t)t * cH;
  {
    float a0=0,a1=0,a2=0,a3=0;
    #pragma unroll
    for (int d = 0; d < cH; d += 4){
      a0 += w1r[d]*lbuf[d]; a1 += w1r[d+1]*lbuf[d+1]; a2 += w1r[d+2]*lbuf[d+2]; a3 += w1r[d+3]*lbuf[d+3];
    }
    gbuf[t] = gelu_f((a0+a1)+(a2+a3) + mb1[t]);
  }
  __syncthreads();
  const float* w2r = mw2 + (size_t)t * cH;
  float m2v;
  {
    float a0=0,a1=0,a2=0,a3=0;
    #pragma unroll
    for (int d = 0; d < cH; d += 4){
      a0 += w2r[d]*gbuf[d]; a1 += w2r[d+1]*gbuf[d+1]; a2 += w2r[d+2]*gbuf[d+2]; a3 += w2r[d+3]*gbuf[d+3];
    }
    m2v = (a0+a1)+(a2+a3) + mb2[t];
  }
  float outv = nv + 0.2f * m2v;
  newobj[((size_t)b * cO + o) * cH + t] = outv;

  float qv = outv * outv;
  #pragma unroll
  for (int m = 1; m < 64; m <<= 1) qv += __shfl_xor(qv, m);
  __syncthreads();
  if (lane == 0) red[wid] = qv;
  __syncthreads();
  if (t == 0) nsq[b * cO + o] = red[0] + red[1];

  if (writeSlots){
    #pragma unroll
    for (int l = 0; l < 3; ++l){
      size_t base = ((size_t)b * cK + o * 3 + l) * 129;
      slots_out[base + 1 + t] = outv;
      if (t == 0) slots_out[base] = lt[l];
    }
  }
}

extern "C" void kernel_launch(void* const* d_in, const int* in_sizes, int n_in,
                              void* d_out, int out_size, void* d_ws, size_t ws_size,
                              hipStream_t stream){
  const float* x       = (const float*)d_in[0];
  const float* enc_w1  = (const float*)d_in[1];
  const float* enc_b1  = (const float*)d_in[2];
  const float* enc_g1  = (const float*)d_in[3];
  const float* enc_bb1 = (const float*)d_in[4];
  const float* enc_w2  = (const float*)d_in[5];
  const float* enc_b2  = (const float*)d_in[6];
  const float* enc_g2  = (const float*)d_in[7];
  const float* enc_bb2 = (const float*)d_in[8];
  const float* sp_w1   = (const float*)d_in[9];
  const float* sp_b1   = (const float*)d_in[10];
  const float* sp_g    = (const float*)d_in[11];
  const float* sp_bb   = (const float*)d_in[12];
  const float* sp_w2   = (const float*)d_in[13];
  const float* sp_b2   = (const float*)d_in[14];
  const float* objsp   = (const float*)d_in[15];
  const float* hscale  = (const float*)d_in[16];
  const float* ltimes  = (const float*)d_in[17];
  const float* bhor    = (const float*)d_in[18];
  const float* gw_ih   = (const float*)d_in[19];
  const float* gw_hh   = (const float*)d_in[20];
  const float* gb_ih   = (const float*)d_in[21];
  const float* gb_hh   = (const float*)d_in[22];
  const float* mw1     = (const float*)d_in[23];
  const float* mb1     = (const float*)d_in[24];
  const float* mw2     = (const float*)d_in[25];
  const float* mb2     = (const float*)d_in[26];
  const float* normg   = (const float*)d_in[27];
  const float* normb   = (const float*)d_in[28];
  (void)in_sizes; (void)n_in; (void)out_size; (void)ws_size;

  float* out = (float*)d_out;
  float* ws  = (float*)d_ws;

  float* spatial = ws + WS_SPATIAL;
  float* sq      = ws + WS_SQ;
  float* ghs     = ws + WS_GHS;
  float* nsq0    = ws + WS_NSQ0;
  float* newobj  = ws + WS_NEWOBJ;
  float* nsqv    = ws + WS_NSQ;
  short* wf      = (short*)(ws + WS_WFRAG);
  float* updr3   = ws + WS_UPD3;
  float* Ss3     = ws + WS_S3;
  short* xbf     = (short*)(ws + WS_XBF);

  k_setup<<<dim3(774), dim3(256), 0, stream>>>(x, xbf, sq,
                                               objsp, gw_hh, gb_hh, enc_w1, enc_w2, sp_w1,
                                               ghs, nsq0, wf, updr3);
  k_pairwise<<<dim3(cB * (cN / 16)), dim3(256), 0, stream>>>(xbf, sq, out + OUT_DEN);
  k_enc_head<<<dim3(ROWS / 32), dim3(128), 0, stream>>>(x, out + OUT_DEN, wf,
      enc_b1, enc_g1, enc_bb1, enc_b2, enc_g2, enc_bb2,
      sp_b1, sp_g, sp_bb, sp_w2, sp_b2,
      spatial, out + OUT_PT);

  for (int it = 0; it < 3; ++it){
    float* updr = updr3 + (size_t)it * cB * cK * cH;
    float* Ss   = Ss3 + (size_t)it * cB * cK;
    const float* objp = (it == 0) ? objsp : newobj;
    int obst = (it == 0) ? 0 : cO * cH;
    const float* nqp = (it == 0) ? nsq0 : nsqv;
    int nqst = (it == 0) ? 0 : cO;
    k_attn_upd<<<dim3(cB * 64), dim3(256), 0, stream>>>(spatial, out + OUT_PT, out + OUT_DEN,
                                                        objp, obst, nqp, nqst,
                                                        ltimes, bhor, hscale,
                                                        out + OUT_ATTN, (it == 2) ? 1 : 0,
                                                        updr, Ss);
    k_gru<<<dim3(cB * cO), dim3(128), 0, stream>>>(updr, Ss, ghs, objsp, gw_ih, gb_ih,
                                                   mw1, mb1, mw2, mb2, normg, normb, ltimes,
                                                   newobj, nsqv, out + OUT_SLOTS, (it == 2) ? 1 : 0);
  }
}